// Round 1
// baseline (1276.562 us; speedup 1.0000x reference)
//
#include <hip/hip_runtime.h>
#include <math.h>

#define HW 65536
#define NC 26
#define NB 2
#define NPAIR 52

// ws layout (bytes)
#define PL_OFF    0            // u8 [2][65536]
#define TL_OFF    131072       // u8 [2][65536]
#define CNT_OFF   262144       // u32: cntP[52] cntT[52] offP[52] offT[52] curP[52] curT[52]
#define RES_OFF   263392       // f32 res[52][2]
#define LISTP_OFF 264192       // u16[131072]
#define LISTT_OFF 526336       // u16[131072]
#define MINP_OFF  788480       // f32[131072]
#define MINT_OFF  1312768      // f32[131072]

__global__ void k_labels(const float* __restrict__ pred, const float* __restrict__ targ,
                         unsigned char* __restrict__ pl, unsigned char* __restrict__ tl) {
    int idx = blockIdx.x * blockDim.x + threadIdx.x;
    if (idx >= NB * HW) return;
    int b = idx >> 16, hw = idx & (HW - 1);
    const float* p = pred + (size_t)b * NC * HW + hw;
    const float* t = targ + (size_t)b * NC * HW + hw;
    float bp = p[0]; int ap = 0;
    float bt = t[0]; int at = 0;
#pragma unroll
    for (int c = 1; c < NC; ++c) {
        float vp = p[(size_t)c * HW];
        if (vp > bp) { bp = vp; ap = c; }
        float vt = t[(size_t)c * HW];
        if (vt > bt) { bt = vt; at = c; }
    }
    pl[idx] = (unsigned char)ap;
    tl[idx] = (unsigned char)at;
}

__device__ __forceinline__ bool is_boundary(const unsigned char* __restrict__ L, int hw, int c) {
    int y = hw >> 8, x = hw & 255;
    if (y == 0 || y == 255 || x == 0 || x == 255) return true;
    return (int)L[hw - 256] != c || (int)L[hw + 256] != c ||
           (int)L[hw - 1]   != c || (int)L[hw + 1]   != c;
}

__global__ void k_count(const unsigned char* __restrict__ pl, const unsigned char* __restrict__ tl,
                        unsigned int* __restrict__ cnt) {
    int idx = blockIdx.x * blockDim.x + threadIdx.x;
    if (idx >= NB * HW) return;
    int b = idx >> 16, hw = idx & (HW - 1);
    const unsigned char* Lp = pl + b * HW;
    const unsigned char* Lt = tl + b * HW;
    int cp = Lp[hw];
    if (is_boundary(Lp, hw, cp)) atomicAdd(&cnt[b * NC + cp], 1u);
    int ct = Lt[hw];
    if (is_boundary(Lt, hw, ct)) atomicAdd(&cnt[52 + b * NC + ct], 1u);
}

__global__ void k_prefix(unsigned int* __restrict__ cnt) {
    if (threadIdx.x != 0 || blockIdx.x != 0) return;
    unsigned int s = 0;
    for (int i = 0; i < 52; ++i) { cnt[104 + i] = s; cnt[208 + i] = s; s += cnt[i]; }
    s = 0;
    for (int i = 0; i < 52; ++i) { cnt[156 + i] = s; cnt[260 + i] = s; s += cnt[52 + i]; }
}

__global__ void k_scatter(const unsigned char* __restrict__ pl, const unsigned char* __restrict__ tl,
                          unsigned int* __restrict__ cnt,
                          unsigned short* __restrict__ listP, unsigned short* __restrict__ listT) {
    int idx = blockIdx.x * blockDim.x + threadIdx.x;
    if (idx >= NB * HW) return;
    int b = idx >> 16, hw = idx & (HW - 1);
    const unsigned char* Lp = pl + b * HW;
    const unsigned char* Lt = tl + b * HW;
    int cp = Lp[hw];
    if (is_boundary(Lp, hw, cp)) {
        unsigned pos = atomicAdd(&cnt[208 + b * NC + cp], 1u);
        listP[pos] = (unsigned short)hw;
    }
    int ct = Lt[hw];
    if (is_boundary(Lt, hw, ct)) {
        unsigned pos = atomicAdd(&cnt[260 + b * NC + ct], 1u);
        listT[pos] = (unsigned short)hw;
    }
}

// grid: (chunks=256, pair=52, dir=2), block 256
__global__ void k_pairwise(const unsigned int* __restrict__ cnt,
                           const unsigned short* __restrict__ listP,
                           const unsigned short* __restrict__ listT,
                           float* __restrict__ minP, float* __restrict__ minT) {
    int pair = blockIdx.y;
    int dir = blockIdx.z;
    unsigned ns   = dir == 0 ? cnt[pair]       : cnt[52 + pair];
    unsigned i0 = blockIdx.x * 256u;
    if (i0 >= ns) return;
    unsigned nt   = dir == 0 ? cnt[52 + pair]  : cnt[pair];
    unsigned offs = dir == 0 ? cnt[104 + pair] : cnt[156 + pair];
    unsigned offt = dir == 0 ? cnt[156 + pair] : cnt[104 + pair];
    const unsigned short* src = dir == 0 ? listP : listT;
    const unsigned short* tgt = dir == 0 ? listT : listP;
    float* outv = dir == 0 ? minP : minT;

    int tid = threadIdx.x;
    unsigned i = i0 + tid;
    bool active = i < ns;
    float sx = 0.f, sy = 0.f;
    if (active) {
        unsigned h = src[offs + i];
        sx = (float)(h & 255u);
        sy = (float)(h >> 8);
    }
    __shared__ float tx[256], ty[256];
    float best = 1e10f;
    for (unsigned tb = 0; tb < nt; tb += 256u) {
        unsigned m = nt - tb; if (m > 256u) m = 256u;
        if ((unsigned)tid < m) {
            unsigned h = tgt[offt + tb + tid];
            tx[tid] = (float)(h & 255u);
            ty[tid] = (float)(h >> 8);
        }
        __syncthreads();
        for (unsigned j = 0; j < m; ++j) {
            float dx = tx[j] - sx;
            float dy = ty[j] - sy;
            float d2 = dx * dx + dy * dy;
            best = fminf(best, d2);
        }
        __syncthreads();
    }
    if (active) outv[offs + i] = best;
}

// grid: (pair=52, dir=2), block 256
__global__ void k_select(const unsigned int* __restrict__ cnt,
                         const float* __restrict__ minP, const float* __restrict__ minT,
                         float* __restrict__ res) {
    int pair = blockIdx.x;
    int dir = blockIdx.y;
    unsigned ns   = dir == 0 ? cnt[pair]       : cnt[52 + pair];
    unsigned nt   = dir == 0 ? cnt[52 + pair]  : cnt[pair];
    unsigned offs = dir == 0 ? cnt[104 + pair] : cnt[156 + pair];
    const float* vals = dir == 0 ? minP : minT;
    int tid = threadIdx.x;

    if (ns == 0) { if (tid == 0) res[pair * 2 + dir] = nanf(""); return; }
    if (nt == 0) { if (tid == 0) res[pair * 2 + dir] = sqrtf(1e10f); return; }

    __shared__ unsigned hist[1024];
    __shared__ unsigned f1[128], f2[128];
    __shared__ int s_binlo, s_binhi, s_below_lo, s_below_hi;

    for (int i = tid; i < 1024; i += 256) hist[i] = 0;
    __syncthreads();
    for (unsigned i = tid; i < ns; i += 256) {
        int v = (int)vals[offs + i];
        atomicAdd(&hist[v >> 7], 1u);
    }
    __syncthreads();

    float idxf = 0.95f * ((float)ns - 1.0f);
    if (idxf < 0.f) idxf = 0.f;
    int klo = (int)floorf(idxf);
    int khi = (int)ceilf(idxf);

    if (tid == 0) {
        unsigned cum = 0;
        int binlo = -1, binhi = -1, below_lo = 0, below_hi = 0;
        for (int bkt = 0; bkt < 1024; ++bkt) {
            unsigned h = hist[bkt];
            if (binlo < 0 && cum + h > (unsigned)klo) { binlo = bkt; below_lo = (int)cum; }
            if (binhi < 0 && cum + h > (unsigned)khi) { binhi = bkt; below_hi = (int)cum; }
            cum += h;
            if (binhi >= 0) break;
        }
        s_binlo = binlo; s_binhi = binhi; s_below_lo = below_lo; s_below_hi = below_hi;
    }
    __syncthreads();
    if (tid < 128) { f1[tid] = 0; f2[tid] = 0; }
    __syncthreads();
    int binlo = s_binlo, binhi = s_binhi;
    for (unsigned i = tid; i < ns; i += 256) {
        int v = (int)vals[offs + i];
        int bkt = v >> 7;
        if (bkt == binlo) atomicAdd(&f1[v & 127], 1u);
        if (bkt == binhi && binhi != binlo) atomicAdd(&f2[v & 127], 1u);
    }
    __syncthreads();
    if (tid == 0) {
        int rlo = klo - s_below_lo;
        unsigned cum = 0; int d2lo = binlo << 7, d2hi = binhi << 7;
        for (int j = 0; j < 128; ++j) {
            cum += f1[j];
            if ((int)cum > rlo) { d2lo = (binlo << 7) + j; break; }
        }
        if (binhi == binlo) {
            int rhi = khi - s_below_lo;
            cum = 0;
            for (int j = 0; j < 128; ++j) {
                cum += f1[j];
                if ((int)cum > rhi) { d2hi = (binlo << 7) + j; break; }
            }
        } else {
            int rhi = khi - s_below_hi;
            cum = 0;
            for (int j = 0; j < 128; ++j) {
                cum += f2[j];
                if ((int)cum > rhi) { d2hi = (binhi << 7) + j; break; }
            }
        }
        float vlo = sqrtf((float)d2lo);
        float vhi = sqrtf((float)d2hi);
        float frac = idxf - floorf(idxf);
        res[pair * 2 + dir] = vlo + (vhi - vlo) * frac;
    }
}

__global__ void k_final(const unsigned int* __restrict__ cnt, const float* __restrict__ res,
                        float* __restrict__ out) {
    if (threadIdx.x != 0 || blockIdx.x != 0) return;
    float total = 0.f, nvalid = 0.f;
    bool anyv = false;
    for (int b = 0; b < NB; ++b) {
        float num = 0.f, den = 0.f;
        for (int c = 0; c < NC; ++c) {
            int pair = b * NC + c;
            bool present = cnt[52 + pair] > 0;
            float dpt = res[pair * 2];
            float dtp = res[pair * 2 + 1];
            float hd;
            if (isnan(dpt) || isnan(dtp)) hd = nanf("");
            else hd = fmaxf(dpt, dtp);
            if (present) { num += hd; den += 1.f; }
        }
        float bm = num / fmaxf(den, 1.f);
        if (den > 0.f) { total += bm; nvalid += 1.f; anyv = true; }
    }
    out[0] = anyv ? (total / fmaxf(nvalid, 1.f)) : INFINITY;
}

extern "C" void kernel_launch(void* const* d_in, const int* in_sizes, int n_in,
                              void* d_out, int out_size, void* d_ws, size_t ws_size,
                              hipStream_t stream) {
    const float* pred = (const float*)d_in[0];
    const float* targ = (const float*)d_in[1];
    float* out = (float*)d_out;
    char* ws = (char*)d_ws;

    unsigned char* pl = (unsigned char*)(ws + PL_OFF);
    unsigned char* tl = (unsigned char*)(ws + TL_OFF);
    unsigned int* cnt = (unsigned int*)(ws + CNT_OFF);
    float* res = (float*)(ws + RES_OFF);
    unsigned short* listP = (unsigned short*)(ws + LISTP_OFF);
    unsigned short* listT = (unsigned short*)(ws + LISTT_OFF);
    float* minP = (float*)(ws + MINP_OFF);
    float* minT = (float*)(ws + MINT_OFF);

    hipMemsetAsync(ws + CNT_OFF, 0, 1248, stream);
    k_labels<<<512, 256, 0, stream>>>(pred, targ, pl, tl);
    k_count<<<512, 256, 0, stream>>>(pl, tl, cnt);
    k_prefix<<<1, 64, 0, stream>>>(cnt);
    k_scatter<<<512, 256, 0, stream>>>(pl, tl, cnt, listP, listT);
    k_pairwise<<<dim3(256, 52, 2), 256, 0, stream>>>(cnt, listP, listT, minP, minT);
    k_select<<<dim3(52, 2), 256, 0, stream>>>(cnt, minP, minT, res);
    k_final<<<1, 64, 0, stream>>>(cnt, res, out);
}

// Round 2
// 306.046 us; speedup vs baseline: 4.1711x; 4.1711x over previous
//
#include <hip/hip_runtime.h>
#include <math.h>

#define HW 65536
#define NC 26
#define NB 2

// cnt u32 indices: [0..51] cntP, [52..103] cntT, [104..155] offP, [156..207] offT,
//                  [208..259] curP, [260..311] curT
#define PL_OFF    0            // u8 [2][65536]
#define TL_OFF    131072       // u8 [2][65536]
#define CNT_OFF   262144       // 312 u32 = 1248 B
#define RES_OFF   263424       // f32 res[52][2]
#define LISTP_OFF 264192       // u16[145408]
#define LISTT_OFF 555008       // u16[145408]
#define MINP_OFF  845824       // f32[145408]
#define MINT_OFF  1427456      // f32[145408]
#define LIST_CAP  145408

__global__ void k_labels(const float4* __restrict__ pred, const float4* __restrict__ targ,
                         uchar4* __restrict__ pl, uchar4* __restrict__ tl) {
    int idx = blockIdx.x * 256 + threadIdx.x;   // 0..32767 (NB*HW/4)
    if (idx >= (NB * HW / 4)) return;
    int b = idx >> 14, q = idx & 16383;
    const float4* p = pred + ((size_t)b * NC << 14) + q;
    const float4* t = targ + ((size_t)b * NC << 14) + q;
    float4 bp = p[0]; uchar4 ap = {0, 0, 0, 0};
    float4 bt = t[0]; uchar4 at = {0, 0, 0, 0};
#pragma unroll
    for (int c = 1; c < NC; ++c) {
        float4 vp = p[(size_t)c << 14];
        if (vp.x > bp.x) { bp.x = vp.x; ap.x = (unsigned char)c; }
        if (vp.y > bp.y) { bp.y = vp.y; ap.y = (unsigned char)c; }
        if (vp.z > bp.z) { bp.z = vp.z; ap.z = (unsigned char)c; }
        if (vp.w > bp.w) { bp.w = vp.w; ap.w = (unsigned char)c; }
        float4 vt = t[(size_t)c << 14];
        if (vt.x > bt.x) { bt.x = vt.x; at.x = (unsigned char)c; }
        if (vt.y > bt.y) { bt.y = vt.y; at.y = (unsigned char)c; }
        if (vt.z > bt.z) { bt.z = vt.z; at.z = (unsigned char)c; }
        if (vt.w > bt.w) { bt.w = vt.w; at.w = (unsigned char)c; }
    }
    pl[idx] = ap;
    tl[idx] = at;
}

__device__ __forceinline__ bool is_boundary(const unsigned char* __restrict__ L, int hw, int c) {
    int y = hw >> 8, x = hw & 255;
    if (y == 0 || y == 255 || x == 0 || x == 255) return true;
    return (int)L[hw - 256] != c || (int)L[hw + 256] != c ||
           (int)L[hw - 1]   != c || (int)L[hw + 1]   != c;
}

__global__ void k_count(const unsigned char* __restrict__ pl, const unsigned char* __restrict__ tl,
                        unsigned int* __restrict__ cnt) {
    __shared__ unsigned lh[104];
    int tid = threadIdx.x;
    int idx = blockIdx.x * 256 + tid;
    if (tid < 104) lh[tid] = 0;
    __syncthreads();
    int b = idx >> 16, hw = idx & (HW - 1);
    const unsigned char* Lp = pl + (b << 16);
    const unsigned char* Lt = tl + (b << 16);
    int cp = Lp[hw];
    if (is_boundary(Lp, hw, cp)) atomicAdd(&lh[b * NC + cp], 1u);
    int ct = Lt[hw];
    if (is_boundary(Lt, hw, ct)) atomicAdd(&lh[52 + b * NC + ct], 1u);
    __syncthreads();
    if (tid < 104 && lh[tid]) atomicAdd(&cnt[tid], lh[tid]);
}

__global__ void k_prefix(unsigned int* __restrict__ cnt) {
    if (threadIdx.x != 0 || blockIdx.x != 0) return;
    unsigned s = 0;
    for (int i = 0; i < 52; ++i) {
        cnt[104 + i] = s; cnt[208 + i] = s;
        s += (cnt[i] + 255u) & ~255u;
    }
    s = 0;
    for (int i = 0; i < 52; ++i) {
        cnt[156 + i] = s; cnt[260 + i] = s;
        s += (cnt[52 + i] + 255u) & ~255u;
    }
}

__global__ void k_scatter(const unsigned char* __restrict__ pl, const unsigned char* __restrict__ tl,
                          unsigned int* __restrict__ cnt,
                          unsigned short* __restrict__ listP, unsigned short* __restrict__ listT) {
    __shared__ unsigned lh[104];
    __shared__ unsigned lbase[104];
    int tid = threadIdx.x;
    int idx = blockIdx.x * 256 + tid;
    if (tid < 104) lh[tid] = 0;
    __syncthreads();
    int b = idx >> 16, hw = idx & (HW - 1);
    const unsigned char* Lp = pl + (b << 16);
    const unsigned char* Lt = tl + (b << 16);
    int cp = Lp[hw];
    int ct = Lt[hw];
    bool bnp = is_boundary(Lp, hw, cp);
    bool bnt = is_boundary(Lt, hw, ct);
    unsigned rp = 0, rt = 0;
    if (bnp) rp = atomicAdd(&lh[b * NC + cp], 1u);
    if (bnt) rt = atomicAdd(&lh[52 + b * NC + ct], 1u);
    __syncthreads();
    if (tid < 104) {
        unsigned c = lh[tid];
        lbase[tid] = c ? atomicAdd(&cnt[208 + tid], c) : 0u;
    }
    __syncthreads();
    if (bnp) listP[lbase[b * NC + cp] + rp] = (unsigned short)hw;
    if (bnt) listT[lbase[52 + b * NC + ct] + rt] = (unsigned short)hw;
}

// grid: (x = schunk*2 + thalf, y = pair, z = dir), block 256, 2 sources/thread
__global__ __launch_bounds__(256) void k_pairwise(
        const unsigned int* __restrict__ cnt,
        const unsigned short* __restrict__ listP,
        const unsigned short* __restrict__ listT,
        float* __restrict__ minP, float* __restrict__ minT) {
    int pair = blockIdx.y;
    int dir = blockIdx.z;
    unsigned ns = dir == 0 ? cnt[pair] : cnt[52 + pair];
    unsigned schunk = blockIdx.x >> 1;
    unsigned thalf = blockIdx.x & 1;
    unsigned i0 = schunk << 9;            // 512 sources per chunk
    if (i0 >= ns) return;
    unsigned nt = dir == 0 ? cnt[52 + pair] : cnt[pair];
    unsigned ntp = (nt + 255u) & ~255u;
    if (thalf * 256u >= ntp) return;
    unsigned offs = dir == 0 ? cnt[104 + pair] : cnt[156 + pair];
    unsigned offt = dir == 0 ? cnt[156 + pair] : cnt[104 + pair];
    const unsigned short* src = dir == 0 ? listP : listT;
    const unsigned short* tgt = dir == 0 ? listT : listP;
    float* outv = dir == 0 ? minP : minT;

    int tid = threadIdx.x;
    float m2x[2], m2y[2], s2[2], best[2];
#pragma unroll
    for (int k = 0; k < 2; ++k) {
        unsigned i = i0 + (k << 8) + tid;
        unsigned h = i < ns ? (unsigned)src[offs + i] : 0u;
        float x = (float)(h & 255u), y = (float)(h >> 8);
        m2x[k] = -2.f * x; m2y[k] = -2.f * y; s2[k] = x * x + y * y;
        best[k] = 3e9f;
    }

    __shared__ float4 tt[256];
    for (unsigned tb = thalf * 256u; tb < ntp; tb += 512u) {
        __syncthreads();
        unsigned h = (unsigned)tgt[offt + tb + tid];
        float4 v;
        if (h == 0xFFFFu) { v.x = 0.f; v.y = 0.f; v.z = 2e9f; v.w = 0.f; }
        else {
            float x = (float)(h & 255u), y = (float)(h >> 8);
            v.x = x; v.y = y; v.z = x * x + y * y; v.w = 0.f;
        }
        tt[tid] = v;
        __syncthreads();
#pragma unroll 16
        for (int j = 0; j < 256; ++j) {
            float4 t = tt[j];
#pragma unroll
            for (int k = 0; k < 2; ++k) {
                float d = fmaf(t.x, m2x[k], t.z);
                d = fmaf(t.y, m2y[k], d);
                best[k] = fminf(best[k], d);
            }
        }
    }
#pragma unroll
    for (int k = 0; k < 2; ++k) {
        unsigned i = i0 + (k << 8) + tid;
        if (i < ns) {
            float d2 = best[k] + s2[k];          // exact integer d^2, >= 0
            atomicMin((unsigned int*)&outv[offs + i], __float_as_uint(d2));
        }
    }
}

// grid: (pair=52, dir=2), block 256
__global__ void k_select(const unsigned int* __restrict__ cnt,
                         const float* __restrict__ minP, const float* __restrict__ minT,
                         float* __restrict__ res) {
    int pair = blockIdx.x;
    int dir = blockIdx.y;
    unsigned ns   = dir == 0 ? cnt[pair]       : cnt[52 + pair];
    unsigned nt   = dir == 0 ? cnt[52 + pair]  : cnt[pair];
    unsigned offs = dir == 0 ? cnt[104 + pair] : cnt[156 + pair];
    const float* vals = dir == 0 ? minP : minT;
    int tid = threadIdx.x;

    if (ns == 0) { if (tid == 0) res[pair * 2 + dir] = nanf(""); return; }
    if (nt == 0) { if (tid == 0) res[pair * 2 + dir] = sqrtf(1e10f); return; }

    __shared__ unsigned hist[1024];
    __shared__ unsigned f1[128], f2[128];
    __shared__ int s_binlo, s_binhi, s_below_lo, s_below_hi;

    for (int i = tid; i < 1024; i += 256) hist[i] = 0;
    __syncthreads();
    for (unsigned i = tid; i < ns; i += 256) {
        int v = (int)vals[offs + i];
        atomicAdd(&hist[v >> 7], 1u);
    }
    __syncthreads();

    float idxf = 0.95f * ((float)ns - 1.0f);
    if (idxf < 0.f) idxf = 0.f;
    int klo = (int)floorf(idxf);
    int khi = (int)ceilf(idxf);

    if (tid == 0) {
        unsigned cum = 0;
        int binlo = -1, binhi = -1, below_lo = 0, below_hi = 0;
        for (int bkt = 0; bkt < 1024; ++bkt) {
            unsigned h = hist[bkt];
            if (binlo < 0 && cum + h > (unsigned)klo) { binlo = bkt; below_lo = (int)cum; }
            if (binhi < 0 && cum + h > (unsigned)khi) { binhi = bkt; below_hi = (int)cum; }
            cum += h;
            if (binhi >= 0) break;
        }
        s_binlo = binlo; s_binhi = binhi; s_below_lo = below_lo; s_below_hi = below_hi;
    }
    __syncthreads();
    if (tid < 128) { f1[tid] = 0; f2[tid] = 0; }
    __syncthreads();
    int binlo = s_binlo, binhi = s_binhi;
    for (unsigned i = tid; i < ns; i += 256) {
        int v = (int)vals[offs + i];
        int bkt = v >> 7;
        if (bkt == binlo) atomicAdd(&f1[v & 127], 1u);
        if (bkt == binhi && binhi != binlo) atomicAdd(&f2[v & 127], 1u);
    }
    __syncthreads();
    if (tid == 0) {
        int rlo = klo - s_below_lo;
        unsigned cum = 0; int d2lo = binlo << 7, d2hi = binhi << 7;
        for (int j = 0; j < 128; ++j) {
            cum += f1[j];
            if ((int)cum > rlo) { d2lo = (binlo << 7) + j; break; }
        }
        if (binhi == binlo) {
            int rhi = khi - s_below_lo;
            cum = 0;
            for (int j = 0; j < 128; ++j) {
                cum += f1[j];
                if ((int)cum > rhi) { d2hi = (binlo << 7) + j; break; }
            }
        } else {
            int rhi = khi - s_below_hi;
            cum = 0;
            for (int j = 0; j < 128; ++j) {
                cum += f2[j];
                if ((int)cum > rhi) { d2hi = (binhi << 7) + j; break; }
            }
        }
        float vlo = sqrtf((float)d2lo);
        float vhi = sqrtf((float)d2hi);
        float frac = idxf - floorf(idxf);
        res[pair * 2 + dir] = vlo + (vhi - vlo) * frac;
    }
}

__global__ void k_final(const unsigned int* __restrict__ cnt, const float* __restrict__ res,
                        float* __restrict__ out) {
    if (threadIdx.x != 0 || blockIdx.x != 0) return;
    float total = 0.f, nvalid = 0.f;
    bool anyv = false;
    for (int b = 0; b < NB; ++b) {
        float num = 0.f, den = 0.f;
        for (int c = 0; c < NC; ++c) {
            int pair = b * NC + c;
            bool present = cnt[52 + pair] > 0;
            float dpt = res[pair * 2];
            float dtp = res[pair * 2 + 1];
            float hd;
            if (isnan(dpt) || isnan(dtp)) hd = nanf("");
            else hd = fmaxf(dpt, dtp);
            if (present) { num += hd; den += 1.f; }
        }
        float bm = num / fmaxf(den, 1.f);
        if (den > 0.f) { total += bm; nvalid += 1.f; anyv = true; }
    }
    out[0] = anyv ? (total / fmaxf(nvalid, 1.f)) : INFINITY;
}

extern "C" void kernel_launch(void* const* d_in, const int* in_sizes, int n_in,
                              void* d_out, int out_size, void* d_ws, size_t ws_size,
                              hipStream_t stream) {
    const float* pred = (const float*)d_in[0];
    const float* targ = (const float*)d_in[1];
    float* out = (float*)d_out;
    char* ws = (char*)d_ws;

    unsigned char* pl = (unsigned char*)(ws + PL_OFF);
    unsigned char* tl = (unsigned char*)(ws + TL_OFF);
    unsigned int* cnt = (unsigned int*)(ws + CNT_OFF);
    float* res = (float*)(ws + RES_OFF);
    unsigned short* listP = (unsigned short*)(ws + LISTP_OFF);
    unsigned short* listT = (unsigned short*)(ws + LISTT_OFF);
    float* minP = (float*)(ws + MINP_OFF);
    float* minT = (float*)(ws + MINT_OFF);

    hipMemsetAsync(ws + CNT_OFF, 0, 1248, stream);
    hipMemsetAsync(ws + LISTP_OFF, 0xFF, 2 * LIST_CAP * sizeof(unsigned short), stream); // sentinel pad
    hipMemsetAsync(ws + MINP_OFF, 0x7F, 2 * LIST_CAP * sizeof(float), stream);           // ~3.39e38
    k_labels<<<128, 256, 0, stream>>>((const float4*)pred, (const float4*)targ,
                                      (uchar4*)pl, (uchar4*)tl);
    k_count<<<512, 256, 0, stream>>>(pl, tl, cnt);
    k_prefix<<<1, 64, 0, stream>>>(cnt);
    k_scatter<<<512, 256, 0, stream>>>(pl, tl, cnt, listP, listT);
    k_pairwise<<<dim3(256, 52, 2), 256, 0, stream>>>(cnt, listP, listT, minP, minT);
    k_select<<<dim3(52, 2), 256, 0, stream>>>(cnt, minP, minT, res);
    k_final<<<1, 64, 0, stream>>>(cnt, res, out);
}

// Round 3
// 205.814 us; speedup vs baseline: 6.2025x; 1.4870x over previous
//
#include <hip/hip_runtime.h>
#include <math.h>

#define HW 65536
#define NC 26
#define NB 2

// cnt u32 indices: [0..51] cntP, [52..103] cntT, [104..155] offP, [156..207] offT,
//                  [208..259] curP, [260..311] curT
#define PL_OFF    0            // u8 [2][65536]
#define TL_OFF    131072       // u8 [2][65536]
#define CNT_OFF   262144       // 312 u32 = 1248 B
#define RES_OFF   263424       // f32 res[52][2]
#define LISTP_OFF 264192       // u16[145408]
#define LISTT_OFF 555008       // u16[145408]
#define MINP_OFF  845824       // f32[145408]
#define MINT_OFF  1427456      // f32[145408]
#define LIST_CAP  145408

__global__ void k_labels(const float4* __restrict__ pred, const float4* __restrict__ targ,
                         uchar4* __restrict__ pl, uchar4* __restrict__ tl,
                         unsigned int* __restrict__ cnt) {
    int tid = threadIdx.x;
    if (blockIdx.x == 0) {
        for (int i = tid; i < 312; i += 128) cnt[i] = 0;
    }
    int idx = blockIdx.x * 128 + tid;   // 0..32767 (NB*HW/4)
    if (idx >= (NB * HW / 4)) return;
    int b = idx >> 14, q = idx & 16383;
    const float4* p = pred + ((size_t)b * NC << 14) + q;
    const float4* t = targ + ((size_t)b * NC << 14) + q;
    float4 bp = p[0]; uchar4 ap = {0, 0, 0, 0};
    float4 bt = t[0]; uchar4 at = {0, 0, 0, 0};
#pragma unroll
    for (int c = 1; c < NC; ++c) {
        float4 vp = p[(size_t)c << 14];
        if (vp.x > bp.x) { bp.x = vp.x; ap.x = (unsigned char)c; }
        if (vp.y > bp.y) { bp.y = vp.y; ap.y = (unsigned char)c; }
        if (vp.z > bp.z) { bp.z = vp.z; ap.z = (unsigned char)c; }
        if (vp.w > bp.w) { bp.w = vp.w; ap.w = (unsigned char)c; }
        float4 vt = t[(size_t)c << 14];
        if (vt.x > bt.x) { bt.x = vt.x; at.x = (unsigned char)c; }
        if (vt.y > bt.y) { bt.y = vt.y; at.y = (unsigned char)c; }
        if (vt.z > bt.z) { bt.z = vt.z; at.z = (unsigned char)c; }
        if (vt.w > bt.w) { bt.w = vt.w; at.w = (unsigned char)c; }
    }
    pl[idx] = ap;
    tl[idx] = at;
}

__device__ __forceinline__ bool is_boundary(const unsigned char* __restrict__ L, int hw, int c) {
    int y = hw >> 8, x = hw & 255;
    if (y == 0 || y == 255 || x == 0 || x == 255) return true;
    return (int)L[hw - 256] != c || (int)L[hw + 256] != c ||
           (int)L[hw - 1]   != c || (int)L[hw + 1]   != c;
}

__global__ void k_count(const unsigned char* __restrict__ pl, const unsigned char* __restrict__ tl,
                        unsigned int* __restrict__ cnt) {
    __shared__ unsigned lh[104];
    int tid = threadIdx.x;
    int idx = blockIdx.x * 256 + tid;
    if (tid < 104) lh[tid] = 0;
    __syncthreads();
    int b = idx >> 16, hw = idx & (HW - 1);
    const unsigned char* Lp = pl + (b << 16);
    const unsigned char* Lt = tl + (b << 16);
    int cp = Lp[hw];
    if (is_boundary(Lp, hw, cp)) atomicAdd(&lh[b * NC + cp], 1u);
    int ct = Lt[hw];
    if (is_boundary(Lt, hw, ct)) atomicAdd(&lh[52 + b * NC + ct], 1u);
    __syncthreads();
    if (tid < 104 && lh[tid]) atomicAdd(&cnt[tid], lh[tid]);
}

__global__ void k_prefix(unsigned int* __restrict__ cnt) {
    if (threadIdx.x != 0 || blockIdx.x != 0) return;
    unsigned s = 0;
    for (int i = 0; i < 52; ++i) {
        cnt[104 + i] = s; cnt[208 + i] = s;
        s += (cnt[i] + 255u) & ~255u;
    }
    s = 0;
    for (int i = 0; i < 52; ++i) {
        cnt[156 + i] = s; cnt[260 + i] = s;
        s += (cnt[52 + i] + 255u) & ~255u;
    }
}

__global__ void k_scatter(const unsigned char* __restrict__ pl, const unsigned char* __restrict__ tl,
                          unsigned int* __restrict__ cnt,
                          unsigned short* __restrict__ listP, unsigned short* __restrict__ listT) {
    __shared__ unsigned lh[104];
    __shared__ unsigned lbase[104];
    int tid = threadIdx.x;
    int idx = blockIdx.x * 256 + tid;
    if (tid < 104) lh[tid] = 0;
    __syncthreads();
    int b = idx >> 16, hw = idx & (HW - 1);
    const unsigned char* Lp = pl + (b << 16);
    const unsigned char* Lt = tl + (b << 16);
    int cp = Lp[hw];
    int ct = Lt[hw];
    bool bnp = is_boundary(Lp, hw, cp);
    bool bnt = is_boundary(Lt, hw, ct);
    unsigned rp = 0, rt = 0;
    if (bnp) rp = atomicAdd(&lh[b * NC + cp], 1u);
    if (bnt) rt = atomicAdd(&lh[52 + b * NC + ct], 1u);
    __syncthreads();
    if (tid < 104) {
        unsigned c = lh[tid];
        lbase[tid] = c ? atomicAdd(&cnt[208 + tid], c) : 0u;
    }
    __syncthreads();
    if (bnp) listP[lbase[b * NC + cp] + rp] = (unsigned short)hw;
    if (bnt) listT[lbase[52 + b * NC + ct] + rt] = (unsigned short)hw;
}

// KA = number of active 256-source groups this block owns (1..8)
template<int KA>
__device__ __forceinline__ void pair_loop(
        const unsigned short* __restrict__ src, unsigned offs, unsigned i_base, unsigned ns,
        const unsigned short* __restrict__ tgt, unsigned offt, unsigned ntiles,
        unsigned ts, float* __restrict__ outv, int tid, float4* tt) {
    float m2x[KA], m2y[KA], s2[KA], best[KA];
#pragma unroll
    for (int k = 0; k < KA; ++k) {
        unsigned i = i_base + ((unsigned)k << 8) + tid;
        unsigned h = i < ns ? (unsigned)src[offs + i] : 0u;
        float x = (float)(h & 255u), y = (float)(h >> 8);
        m2x[k] = -2.f * x; m2y[k] = -2.f * y; s2[k] = x * x + y * y;
        best[k] = 3e9f;
    }
    for (unsigned t = ts; t < ntiles; t += 8u) {
        __syncthreads();
        {
            unsigned h = (unsigned)tgt[offt + (t << 8) + tid];
            float4 v;
            if (h == 0xFFFFu) { v.x = 0.f; v.y = 0.f; v.z = 2e9f; v.w = 0.f; }
            else {
                float x = (float)(h & 255u), y = (float)(h >> 8);
                v.x = x; v.y = y; v.z = fmaf(x, x, y * y); v.w = 0.f;
            }
            tt[tid] = v;
        }
        __syncthreads();
#pragma unroll 4
        for (int j = 0; j < 256; ++j) {
            float4 t4 = tt[j];
#pragma unroll
            for (int k = 0; k < KA; ++k) {
                float d = fmaf(t4.x, m2x[k], t4.z);
                d = fmaf(t4.y, m2y[k], d);
                best[k] = fminf(best[k], d);
            }
        }
    }
#pragma unroll
    for (int k = 0; k < KA; ++k) {
        unsigned i = i_base + ((unsigned)k << 8) + tid;
        if (i < ns)
            atomicMin((unsigned int*)&outv[offs + i], __float_as_uint(best[k] + s2[k]));
    }
}

// grid: (x = chunk*8 + tsplit, y = pair, z = dir), block 256, up to 8 source-groups/block
__global__ __launch_bounds__(256, 4) void k_pairwise(
        const unsigned int* __restrict__ cnt,
        const unsigned short* __restrict__ listP,
        const unsigned short* __restrict__ listT,
        float* __restrict__ minP, float* __restrict__ minT) {
    int pair = blockIdx.y;
    int dir = blockIdx.z;
    unsigned ns = dir == 0 ? cnt[pair] : cnt[52 + pair];
    unsigned chunk = blockIdx.x >> 3;
    unsigned ts = blockIdx.x & 7;
    unsigned i_base = chunk << 11;     // 2048 sources per chunk
    if (i_base >= ns) return;
    unsigned nt = dir == 0 ? cnt[52 + pair] : cnt[pair];
    unsigned offs = dir == 0 ? cnt[104 + pair] : cnt[156 + pair];
    unsigned offt = dir == 0 ? cnt[156 + pair] : cnt[104 + pair];
    const unsigned short* src = dir == 0 ? listP : listT;
    const unsigned short* tgt = dir == 0 ? listT : listP;
    float* outv = dir == 0 ? minP : minT;
    unsigned ntiles = (nt + 255u) >> 8;

    int tid = threadIdx.x;
    __shared__ float4 tt[256];
    unsigned rem = ns - i_base;
    int ka = (int)((rem + 255u) >> 8); if (ka > 8) ka = 8;
    switch (ka) {
        case 1: pair_loop<1>(src, offs, i_base, ns, tgt, offt, ntiles, ts, outv, tid, tt); break;
        case 2: pair_loop<2>(src, offs, i_base, ns, tgt, offt, ntiles, ts, outv, tid, tt); break;
        case 3: pair_loop<3>(src, offs, i_base, ns, tgt, offt, ntiles, ts, outv, tid, tt); break;
        case 4: pair_loop<4>(src, offs, i_base, ns, tgt, offt, ntiles, ts, outv, tid, tt); break;
        case 5: pair_loop<5>(src, offs, i_base, ns, tgt, offt, ntiles, ts, outv, tid, tt); break;
        case 6: pair_loop<6>(src, offs, i_base, ns, tgt, offt, ntiles, ts, outv, tid, tt); break;
        case 7: pair_loop<7>(src, offs, i_base, ns, tgt, offt, ntiles, ts, outv, tid, tt); break;
        default: pair_loop<8>(src, offs, i_base, ns, tgt, offt, ntiles, ts, outv, tid, tt); break;
    }
}

// grid: (pair=52, dir=2), block 256
__global__ void k_select(const unsigned int* __restrict__ cnt,
                         const float* __restrict__ minP, const float* __restrict__ minT,
                         float* __restrict__ res) {
    int pair = blockIdx.x;
    int dir = blockIdx.y;
    unsigned ns   = dir == 0 ? cnt[pair]       : cnt[52 + pair];
    unsigned nt   = dir == 0 ? cnt[52 + pair]  : cnt[pair];
    unsigned offs = dir == 0 ? cnt[104 + pair] : cnt[156 + pair];
    const float* vals = dir == 0 ? minP : minT;
    int tid = threadIdx.x;

    if (ns == 0) { if (tid == 0) res[pair * 2 + dir] = nanf(""); return; }
    if (nt == 0) { if (tid == 0) res[pair * 2 + dir] = sqrtf(1e10f); return; }

    __shared__ unsigned hist[1024];
    __shared__ unsigned f1[128], f2[128];
    __shared__ int s_binlo, s_binhi, s_below_lo, s_below_hi;

    for (int i = tid; i < 1024; i += 256) hist[i] = 0;
    __syncthreads();
    for (unsigned i = tid; i < ns; i += 256) {
        int v = (int)vals[offs + i];
        atomicAdd(&hist[v >> 7], 1u);
    }
    __syncthreads();

    float idxf = 0.95f * ((float)ns - 1.0f);
    if (idxf < 0.f) idxf = 0.f;
    int klo = (int)floorf(idxf);
    int khi = (int)ceilf(idxf);

    if (tid == 0) {
        unsigned cum = 0;
        int binlo = -1, binhi = -1, below_lo = 0, below_hi = 0;
        for (int bkt = 0; bkt < 1024; ++bkt) {
            unsigned h = hist[bkt];
            if (binlo < 0 && cum + h > (unsigned)klo) { binlo = bkt; below_lo = (int)cum; }
            if (binhi < 0 && cum + h > (unsigned)khi) { binhi = bkt; below_hi = (int)cum; }
            cum += h;
            if (binhi >= 0) break;
        }
        s_binlo = binlo; s_binhi = binhi; s_below_lo = below_lo; s_below_hi = below_hi;
    }
    __syncthreads();
    if (tid < 128) { f1[tid] = 0; f2[tid] = 0; }
    __syncthreads();
    int binlo = s_binlo, binhi = s_binhi;
    for (unsigned i = tid; i < ns; i += 256) {
        int v = (int)vals[offs + i];
        int bkt = v >> 7;
        if (bkt == binlo) atomicAdd(&f1[v & 127], 1u);
        if (bkt == binhi && binhi != binlo) atomicAdd(&f2[v & 127], 1u);
    }
    __syncthreads();
    if (tid == 0) {
        int rlo = klo - s_below_lo;
        unsigned cum = 0; int d2lo = binlo << 7, d2hi = binhi << 7;
        for (int j = 0; j < 128; ++j) {
            cum += f1[j];
            if ((int)cum > rlo) { d2lo = (binlo << 7) + j; break; }
        }
        if (binhi == binlo) {
            int rhi = khi - s_below_lo;
            cum = 0;
            for (int j = 0; j < 128; ++j) {
                cum += f1[j];
                if ((int)cum > rhi) { d2hi = (binlo << 7) + j; break; }
            }
        } else {
            int rhi = khi - s_below_hi;
            cum = 0;
            for (int j = 0; j < 128; ++j) {
                cum += f2[j];
                if ((int)cum > rhi) { d2hi = (binhi << 7) + j; break; }
            }
        }
        float vlo = sqrtf((float)d2lo);
        float vhi = sqrtf((float)d2hi);
        float frac = idxf - floorf(idxf);
        res[pair * 2 + dir] = vlo + (vhi - vlo) * frac;
    }
}

__global__ void k_final(const unsigned int* __restrict__ cnt, const float* __restrict__ res,
                        float* __restrict__ out) {
    if (threadIdx.x != 0 || blockIdx.x != 0) return;
    float total = 0.f, nvalid = 0.f;
    bool anyv = false;
    for (int b = 0; b < NB; ++b) {
        float num = 0.f, den = 0.f;
        for (int c = 0; c < NC; ++c) {
            int pair = b * NC + c;
            bool present = cnt[52 + pair] > 0;
            float dpt = res[pair * 2];
            float dtp = res[pair * 2 + 1];
            float hd;
            if (isnan(dpt) || isnan(dtp)) hd = nanf("");
            else hd = fmaxf(dpt, dtp);
            if (present) { num += hd; den += 1.f; }
        }
        float bm = num / fmaxf(den, 1.f);
        if (den > 0.f) { total += bm; nvalid += 1.f; anyv = true; }
    }
    out[0] = anyv ? (total / fmaxf(nvalid, 1.f)) : INFINITY;
}

extern "C" void kernel_launch(void* const* d_in, const int* in_sizes, int n_in,
                              void* d_out, int out_size, void* d_ws, size_t ws_size,
                              hipStream_t stream) {
    const float* pred = (const float*)d_in[0];
    const float* targ = (const float*)d_in[1];
    float* out = (float*)d_out;
    char* ws = (char*)d_ws;

    unsigned char* pl = (unsigned char*)(ws + PL_OFF);
    unsigned char* tl = (unsigned char*)(ws + TL_OFF);
    unsigned int* cnt = (unsigned int*)(ws + CNT_OFF);
    float* res = (float*)(ws + RES_OFF);
    unsigned short* listP = (unsigned short*)(ws + LISTP_OFF);
    unsigned short* listT = (unsigned short*)(ws + LISTT_OFF);
    float* minP = (float*)(ws + MINP_OFF);
    float* minT = (float*)(ws + MINT_OFF);

    hipMemsetAsync(ws + LISTP_OFF, 0xFF, 2 * LIST_CAP * sizeof(unsigned short), stream); // sentinel pad
    hipMemsetAsync(ws + MINP_OFF, 0x7F, 2 * LIST_CAP * sizeof(float), stream);           // ~3.39e38
    k_labels<<<256, 128, 0, stream>>>((const float4*)pred, (const float4*)targ,
                                      (uchar4*)pl, (uchar4*)tl, cnt);
    k_count<<<512, 256, 0, stream>>>(pl, tl, cnt);
    k_prefix<<<1, 64, 0, stream>>>(cnt);
    k_scatter<<<512, 256, 0, stream>>>(pl, tl, cnt, listP, listT);
    k_pairwise<<<dim3(64, 52, 2), 256, 0, stream>>>(cnt, listP, listT, minP, minT);
    k_select<<<dim3(52, 2), 256, 0, stream>>>(cnt, minP, minT, res);
    k_final<<<1, 64, 0, stream>>>(cnt, res, out);
}

// Round 4
// 127.939 us; speedup vs baseline: 9.9779x; 1.6087x over previous
//
#include <hip/hip_runtime.h>
#include <math.h>

#define HW 65536
#define NC 26
#define NB 2

// cnt u32 indices: [0..51] cntP, [52..103] cntT, [104..155] offP, [156..207] offT,
//                  [208..259] curP, [260..311] curT
#define PL_OFF    0            // u8 [2][65536]
#define TL_OFF    131072       // u8 [2][65536]
#define CNT_OFF   262144       // 312 u32 = 1248 B
#define RES_OFF   263424       // f32 res[52][2]
#define LISTP_OFF 264192       // u16[145408]
#define LISTT_OFF 555008       // u16[145408]
#define MINP_OFF  845824       // f32[145408]
#define MINT_OFF  1427456      // f32[145408]
#define LIST_CAP  145408

__global__ void k_labels(const float4* __restrict__ pred, const float4* __restrict__ targ,
                         uchar4* __restrict__ pl, uchar4* __restrict__ tl,
                         unsigned int* __restrict__ cnt) {
    int tid = threadIdx.x;
    if (blockIdx.x == 0) {
        for (int i = tid; i < 312; i += 128) cnt[i] = 0;
    }
    int idx = blockIdx.x * 128 + tid;   // 0..32767 (NB*HW/4)
    if (idx >= (NB * HW / 4)) return;
    int b = idx >> 14, q = idx & 16383;
    const float4* p = pred + ((size_t)b * NC << 14) + q;
    const float4* t = targ + ((size_t)b * NC << 14) + q;
    float4 bp = p[0]; uchar4 ap = {0, 0, 0, 0};
    float4 bt = t[0]; uchar4 at = {0, 0, 0, 0};
#pragma unroll
    for (int c = 1; c < NC; ++c) {
        float4 vp = p[(size_t)c << 14];
        if (vp.x > bp.x) { bp.x = vp.x; ap.x = (unsigned char)c; }
        if (vp.y > bp.y) { bp.y = vp.y; ap.y = (unsigned char)c; }
        if (vp.z > bp.z) { bp.z = vp.z; ap.z = (unsigned char)c; }
        if (vp.w > bp.w) { bp.w = vp.w; ap.w = (unsigned char)c; }
        float4 vt = t[(size_t)c << 14];
        if (vt.x > bt.x) { bt.x = vt.x; at.x = (unsigned char)c; }
        if (vt.y > bt.y) { bt.y = vt.y; at.y = (unsigned char)c; }
        if (vt.z > bt.z) { bt.z = vt.z; at.z = (unsigned char)c; }
        if (vt.w > bt.w) { bt.w = vt.w; at.w = (unsigned char)c; }
    }
    pl[idx] = ap;
    tl[idx] = at;
}

__device__ __forceinline__ bool is_boundary(const unsigned char* __restrict__ L, int hw, int c) {
    int y = hw >> 8, x = hw & 255;
    if (y == 0 || y == 255 || x == 0 || x == 255) return true;
    return (int)L[hw - 256] != c || (int)L[hw + 256] != c ||
           (int)L[hw - 1]   != c || (int)L[hw + 1]   != c;
}

__global__ void k_count(const unsigned char* __restrict__ pl, const unsigned char* __restrict__ tl,
                        unsigned int* __restrict__ cnt) {
    __shared__ unsigned lh[104];
    int tid = threadIdx.x;
    int idx = blockIdx.x * 256 + tid;
    if (tid < 104) lh[tid] = 0;
    __syncthreads();
    int b = idx >> 16, hw = idx & (HW - 1);
    const unsigned char* Lp = pl + (b << 16);
    const unsigned char* Lt = tl + (b << 16);
    int cp = Lp[hw];
    if (is_boundary(Lp, hw, cp)) atomicAdd(&lh[b * NC + cp], 1u);
    int ct = Lt[hw];
    if (is_boundary(Lt, hw, ct)) atomicAdd(&lh[52 + b * NC + ct], 1u);
    __syncthreads();
    if (tid < 104 && lh[tid]) atomicAdd(&cnt[tid], lh[tid]);
}

__global__ void k_prefix(unsigned int* __restrict__ cnt) {
    if (threadIdx.x != 0 || blockIdx.x != 0) return;
    unsigned s = 0;
    for (int i = 0; i < 52; ++i) {
        cnt[104 + i] = s; cnt[208 + i] = s;
        s += (cnt[i] + 255u) & ~255u;
    }
    s = 0;
    for (int i = 0; i < 52; ++i) {
        cnt[156 + i] = s; cnt[260 + i] = s;
        s += (cnt[52 + i] + 255u) & ~255u;
    }
}

__global__ void k_scatter(const unsigned char* __restrict__ pl, const unsigned char* __restrict__ tl,
                          unsigned int* __restrict__ cnt,
                          unsigned short* __restrict__ listP, unsigned short* __restrict__ listT) {
    __shared__ unsigned lh[104];
    __shared__ unsigned lbase[104];
    int tid = threadIdx.x;
    int idx = blockIdx.x * 256 + tid;
    if (tid < 104) lh[tid] = 0;
    __syncthreads();
    int b = idx >> 16, hw = idx & (HW - 1);
    const unsigned char* Lp = pl + (b << 16);
    const unsigned char* Lt = tl + (b << 16);
    int cp = Lp[hw];
    int ct = Lt[hw];
    bool bnp = is_boundary(Lp, hw, cp);
    bool bnt = is_boundary(Lt, hw, ct);
    unsigned rp = 0, rt = 0;
    if (bnp) rp = atomicAdd(&lh[b * NC + cp], 1u);
    if (bnt) rt = atomicAdd(&lh[52 + b * NC + ct], 1u);
    __syncthreads();
    if (tid < 104) {
        unsigned c = lh[tid];
        lbase[tid] = c ? atomicAdd(&cnt[208 + tid], c) : 0u;
    }
    __syncthreads();
    if (bnp) listP[lbase[b * NC + cp] + rp] = (unsigned short)hw;
    if (bnt) listT[lbase[52 + b * NC + ct] + rt] = (unsigned short)hw;
}

// KA = number of active 256-source groups this chunk owns (1..8)
template<int KA>
__device__ __forceinline__ void pair_loop(
        const unsigned short* __restrict__ src, unsigned offs, unsigned i_base, unsigned ns,
        const unsigned short* __restrict__ tgt, unsigned offt, unsigned ntiles,
        unsigned ts, float* __restrict__ outv, int tid, float4* tt) {
    float m2x[KA], m2y[KA], s2[KA], best[KA];
#pragma unroll
    for (int k = 0; k < KA; ++k) {
        // list arrays are 0xFF-padded to 256-aligned class regions: unguarded load safe
        unsigned h = (unsigned)src[offs + i_base + ((unsigned)k << 8) + tid];
        float x = (float)(h & 255u), y = (float)(h >> 8);
        m2x[k] = -2.f * x; m2y[k] = -2.f * y; s2[k] = x * x + y * y;
        best[k] = 3e9f;
    }
    for (unsigned t = ts; t < ntiles; t += 4u) {
        __syncthreads();
        {
            unsigned h = (unsigned)tgt[offt + (t << 8) + tid];
            float4 v;
            if (h == 0xFFFFu) { v.x = 0.f; v.y = 0.f; v.z = 2e9f; v.w = 0.f; }
            else {
                float x = (float)(h & 255u), y = (float)(h >> 8);
                v.x = x; v.y = y; v.z = fmaf(x, x, y * y); v.w = 0.f;
            }
            tt[tid] = v;
        }
        __syncthreads();
#pragma unroll 4
        for (int j = 0; j < 256; j += 2) {
            float4 a = tt[j];
            float4 b = tt[j + 1];
#pragma unroll
            for (int k = 0; k < KA; ++k) {
                float da = fmaf(a.y, m2y[k], fmaf(a.x, m2x[k], a.z));
                float db = fmaf(b.y, m2y[k], fmaf(b.x, m2x[k], b.z));
                best[k] = fminf(fminf(best[k], da), db);   // -> v_min3_f32
            }
        }
    }
#pragma unroll
    for (int k = 0; k < KA; ++k) {
        unsigned i = i_base + ((unsigned)k << 8) + tid;
        if (i < ns)
            atomicMin((unsigned int*)&outv[offs + i], __float_as_uint(best[k] + s2[k]));
    }
}

// grid: (x = chunkSlot*4 + tsplit (8), y = pair (52), z = dir (2)), block 256
__global__ __launch_bounds__(256, 4) void k_pairwise(
        const unsigned int* __restrict__ cnt,
        const unsigned short* __restrict__ listP,
        const unsigned short* __restrict__ listT,
        float* __restrict__ minP, float* __restrict__ minT) {
    int pair = blockIdx.y;
    int dir = blockIdx.z;
    unsigned ns = dir == 0 ? cnt[pair] : cnt[52 + pair];
    if (ns == 0) return;
    unsigned nt = dir == 0 ? cnt[52 + pair] : cnt[pair];
    unsigned offs = dir == 0 ? cnt[104 + pair] : cnt[156 + pair];
    unsigned offt = dir == 0 ? cnt[156 + pair] : cnt[104 + pair];
    const unsigned short* src = dir == 0 ? listP : listT;
    const unsigned short* tgt = dir == 0 ? listT : listP;
    float* outv = dir == 0 ? minP : minT;
    unsigned ntiles = (nt + 255u) >> 8;

    unsigned slot = blockIdx.x >> 2;   // 0..1
    unsigned ts = blockIdx.x & 3;      // 0..3
    int tid = threadIdx.x;
    __shared__ float4 tt[256];

    for (unsigned chunk = slot; (chunk << 11) < ns; chunk += 2u) {
        unsigned i_base = chunk << 11;     // 2048 sources per chunk
        unsigned rem = ns - i_base;
        int ka = (int)((rem + 255u) >> 8); if (ka > 8) ka = 8;
        switch (ka) {
            case 1: pair_loop<1>(src, offs, i_base, ns, tgt, offt, ntiles, ts, outv, tid, tt); break;
            case 2: pair_loop<2>(src, offs, i_base, ns, tgt, offt, ntiles, ts, outv, tid, tt); break;
            case 3: pair_loop<3>(src, offs, i_base, ns, tgt, offt, ntiles, ts, outv, tid, tt); break;
            case 4: pair_loop<4>(src, offs, i_base, ns, tgt, offt, ntiles, ts, outv, tid, tt); break;
            case 5: pair_loop<5>(src, offs, i_base, ns, tgt, offt, ntiles, ts, outv, tid, tt); break;
            case 6: pair_loop<6>(src, offs, i_base, ns, tgt, offt, ntiles, ts, outv, tid, tt); break;
            case 7: pair_loop<7>(src, offs, i_base, ns, tgt, offt, ntiles, ts, outv, tid, tt); break;
            default: pair_loop<8>(src, offs, i_base, ns, tgt, offt, ntiles, ts, outv, tid, tt); break;
        }
    }
}

// grid: (pair=52, dir=2), block 256
__global__ void k_select(const unsigned int* __restrict__ cnt,
                         const float* __restrict__ minP, const float* __restrict__ minT,
                         float* __restrict__ res) {
    int pair = blockIdx.x;
    int dir = blockIdx.y;
    unsigned ns   = dir == 0 ? cnt[pair]       : cnt[52 + pair];
    unsigned nt   = dir == 0 ? cnt[52 + pair]  : cnt[pair];
    unsigned offs = dir == 0 ? cnt[104 + pair] : cnt[156 + pair];
    const float* vals = dir == 0 ? minP : minT;
    int tid = threadIdx.x;

    if (ns == 0) { if (tid == 0) res[pair * 2 + dir] = nanf(""); return; }
    if (nt == 0) { if (tid == 0) res[pair * 2 + dir] = sqrtf(1e10f); return; }

    __shared__ unsigned hist[1024];
    __shared__ unsigned f1[128], f2[128];
    __shared__ int s_binlo, s_binhi, s_below_lo, s_below_hi;

    for (int i = tid; i < 1024; i += 256) hist[i] = 0;
    __syncthreads();
    for (unsigned i = tid; i < ns; i += 256) {
        int v = (int)vals[offs + i];
        atomicAdd(&hist[v >> 7], 1u);
    }
    __syncthreads();

    float idxf = 0.95f * ((float)ns - 1.0f);
    if (idxf < 0.f) idxf = 0.f;
    int klo = (int)floorf(idxf);
    int khi = (int)ceilf(idxf);

    if (tid == 0) {
        unsigned cum = 0;
        int binlo = -1, binhi = -1, below_lo = 0, below_hi = 0;
        for (int bkt = 0; bkt < 1024; ++bkt) {
            unsigned h = hist[bkt];
            if (binlo < 0 && cum + h > (unsigned)klo) { binlo = bkt; below_lo = (int)cum; }
            if (binhi < 0 && cum + h > (unsigned)khi) { binhi = bkt; below_hi = (int)cum; }
            cum += h;
            if (binhi >= 0) break;
        }
        s_binlo = binlo; s_binhi = binhi; s_below_lo = below_lo; s_below_hi = below_hi;
    }
    __syncthreads();
    if (tid < 128) { f1[tid] = 0; f2[tid] = 0; }
    __syncthreads();
    int binlo = s_binlo, binhi = s_binhi;
    for (unsigned i = tid; i < ns; i += 256) {
        int v = (int)vals[offs + i];
        int bkt = v >> 7;
        if (bkt == binlo) atomicAdd(&f1[v & 127], 1u);
        if (bkt == binhi && binhi != binlo) atomicAdd(&f2[v & 127], 1u);
    }
    __syncthreads();
    if (tid == 0) {
        int rlo = klo - s_below_lo;
        unsigned cum = 0; int d2lo = binlo << 7, d2hi = binhi << 7;
        for (int j = 0; j < 128; ++j) {
            cum += f1[j];
            if ((int)cum > rlo) { d2lo = (binlo << 7) + j; break; }
        }
        if (binhi == binlo) {
            int rhi = khi - s_below_lo;
            cum = 0;
            for (int j = 0; j < 128; ++j) {
                cum += f1[j];
                if ((int)cum > rhi) { d2hi = (binlo << 7) + j; break; }
            }
        } else {
            int rhi = khi - s_below_hi;
            cum = 0;
            for (int j = 0; j < 128; ++j) {
                cum += f2[j];
                if ((int)cum > rhi) { d2hi = (binhi << 7) + j; break; }
            }
        }
        float vlo = sqrtf((float)d2lo);
        float vhi = sqrtf((float)d2hi);
        float frac = idxf - floorf(idxf);
        res[pair * 2 + dir] = vlo + (vhi - vlo) * frac;
    }
}

__global__ void k_final(const unsigned int* __restrict__ cnt, const float* __restrict__ res,
                        float* __restrict__ out) {
    if (threadIdx.x != 0 || blockIdx.x != 0) return;
    float total = 0.f, nvalid = 0.f;
    bool anyv = false;
    for (int b = 0; b < NB; ++b) {
        float num = 0.f, den = 0.f;
        for (int c = 0; c < NC; ++c) {
            int pair = b * NC + c;
            bool present = cnt[52 + pair] > 0;
            float dpt = res[pair * 2];
            float dtp = res[pair * 2 + 1];
            float hd;
            if (isnan(dpt) || isnan(dtp)) hd = nanf("");
            else hd = fmaxf(dpt, dtp);
            if (present) { num += hd; den += 1.f; }
        }
        float bm = num / fmaxf(den, 1.f);
        if (den > 0.f) { total += bm; nvalid += 1.f; anyv = true; }
    }
    out[0] = anyv ? (total / fmaxf(nvalid, 1.f)) : INFINITY;
}

extern "C" void kernel_launch(void* const* d_in, const int* in_sizes, int n_in,
                              void* d_out, int out_size, void* d_ws, size_t ws_size,
                              hipStream_t stream) {
    const float* pred = (const float*)d_in[0];
    const float* targ = (const float*)d_in[1];
    float* out = (float*)d_out;
    char* ws = (char*)d_ws;

    unsigned char* pl = (unsigned char*)(ws + PL_OFF);
    unsigned char* tl = (unsigned char*)(ws + TL_OFF);
    unsigned int* cnt = (unsigned int*)(ws + CNT_OFF);
    float* res = (float*)(ws + RES_OFF);
    unsigned short* listP = (unsigned short*)(ws + LISTP_OFF);
    unsigned short* listT = (unsigned short*)(ws + LISTT_OFF);
    float* minP = (float*)(ws + MINP_OFF);
    float* minT = (float*)(ws + MINT_OFF);

    hipMemsetAsync(ws + LISTP_OFF, 0xFF, 2 * LIST_CAP * sizeof(unsigned short), stream); // sentinel pad
    hipMemsetAsync(ws + MINP_OFF, 0x7F, 2 * LIST_CAP * sizeof(float), stream);           // ~3.39e38
    k_labels<<<256, 128, 0, stream>>>((const float4*)pred, (const float4*)targ,
                                      (uchar4*)pl, (uchar4*)tl, cnt);
    k_count<<<512, 256, 0, stream>>>(pl, tl, cnt);
    k_prefix<<<1, 64, 0, stream>>>(cnt);
    k_scatter<<<512, 256, 0, stream>>>(pl, tl, cnt, listP, listT);
    k_pairwise<<<dim3(8, 52, 2), 256, 0, stream>>>(cnt, listP, listT, minP, minT);
    k_select<<<dim3(52, 2), 256, 0, stream>>>(cnt, minP, minT, res);
    k_final<<<1, 64, 0, stream>>>(cnt, res, out);
}

// Round 6
// 88.766 us; speedup vs baseline: 14.3812x; 1.4413x over previous
//
#include <hip/hip_runtime.h>
#include <math.h>

#define HW 65536
#define NC 26
#define NB 2

// ws layout (bytes). cnt u32: [0..51] cntP, [52..103] cntT, [104..155] offP, [156..207] offT
#define PL_OFF     0         // u8 [2][65536]
#define TL_OFF     131072    // u8 [2][65536]
#define CNT_OFF    262144    // 208 u32 used
#define RES_OFF    263424    // f32 res[52][2]
#define ROWOFF_OFF 264192    // u32 [2][52][257] = 106912 B
#define LISTP_OFF  371104    // u16[131072]
#define LISTT_OFF  633248    // u16[131072]
#define MINP_OFF   895392    // f32[131072]
#define MINT_OFF   1419680   // f32[131072]  (ends 1943968)
#define ROWCNT_OFF MINP_OFF  // u32 [2][52][256] = 106496 B, dead before minP written

__global__ void k_labels(const float4* __restrict__ pred, const float4* __restrict__ targ,
                         uchar4* __restrict__ pl, uchar4* __restrict__ tl) {
    int idx = blockIdx.x * 128 + threadIdx.x;   // 0..32767
    if (idx >= (NB * HW / 4)) return;
    int b = idx >> 14, q = idx & 16383;
    const float4* p = pred + ((size_t)b * NC << 14) + q;
    const float4* t = targ + ((size_t)b * NC << 14) + q;
    float4 bp = p[0]; uchar4 ap = {0, 0, 0, 0};
    float4 bt = t[0]; uchar4 at = {0, 0, 0, 0};
#pragma unroll
    for (int c = 1; c < NC; ++c) {
        float4 vp = p[(size_t)c << 14];
        if (vp.x > bp.x) { bp.x = vp.x; ap.x = (unsigned char)c; }
        if (vp.y > bp.y) { bp.y = vp.y; ap.y = (unsigned char)c; }
        if (vp.z > bp.z) { bp.z = vp.z; ap.z = (unsigned char)c; }
        if (vp.w > bp.w) { bp.w = vp.w; ap.w = (unsigned char)c; }
        float4 vt = t[(size_t)c << 14];
        if (vt.x > bt.x) { bt.x = vt.x; at.x = (unsigned char)c; }
        if (vt.y > bt.y) { bt.y = vt.y; at.y = (unsigned char)c; }
        if (vt.z > bt.z) { bt.z = vt.z; at.z = (unsigned char)c; }
        if (vt.w > bt.w) { bt.w = vt.w; at.w = (unsigned char)c; }
    }
    pl[idx] = ap;
    tl[idx] = at;
}

__device__ __forceinline__ bool is_boundary(const unsigned char* __restrict__ L, int hw, int c) {
    int y = hw >> 8, x = hw & 255;
    if (y == 0 || y == 255 || x == 0 || x == 255) return true;
    return (int)L[hw - 256] != c || (int)L[hw + 256] != c ||
           (int)L[hw - 1]   != c || (int)L[hw + 1]   != c;
}

// grid 512 = (b<<8)|y, block 256 (tid = x). rowcnt: [2][52][256]
__global__ void k_count_rows(const unsigned char* __restrict__ pl,
                             const unsigned char* __restrict__ tl,
                             unsigned int* __restrict__ rowcnt) {
    __shared__ unsigned lh[52];
    int tid = threadIdx.x;
    int b = blockIdx.x >> 8, y = blockIdx.x & 255;
    if (tid < 52) lh[tid] = 0;
    __syncthreads();
    const unsigned char* Lp = pl + (b << 16);
    const unsigned char* Lt = tl + (b << 16);
    int hw = (y << 8) | tid;
    int cp = Lp[hw];
    if (is_boundary(Lp, hw, cp)) atomicAdd(&lh[cp], 1u);
    int ct = Lt[hw];
    if (is_boundary(Lt, hw, ct)) atomicAdd(&lh[26 + ct], 1u);
    __syncthreads();
    if (tid < 26)
        rowcnt[(((b * 26 + tid) << 8) | y)] = lh[tid];
    else if (tid < 52)
        rowcnt[13312 + (((b * 26 + (tid - 26)) << 8) | y)] = lh[tid];  // FIXED: was lh[tid-26] (P hist)
}

// 1 block, 256 threads. rowcnt[2][52][256] -> rowoff[2][52][257] (absolute), cnt totals+bases
__global__ void k_prefix_rows(const unsigned int* __restrict__ rowcnt,
                              unsigned int* __restrict__ rowoff,
                              unsigned int* __restrict__ cnt) {
    __shared__ unsigned S[52 * 257];
    __shared__ unsigned tot[52], base[52];
    int tid = threadIdx.x;
    for (int m = 0; m < 2; ++m) {
        const unsigned* rc = rowcnt + m * 13312;
        unsigned* ro = rowoff + m * 13364;
        for (int g = tid; g < 13312; g += 256) {
            int pair = g >> 8, row = g & 255;
            S[pair * 257 + row] = rc[g];
        }
        __syncthreads();
        if (tid < 52) {
            unsigned s = 0;
            int o = tid * 257;
            for (int i = 0; i < 256; ++i) { unsigned v = S[o + i]; S[o + i] = s; s += v; }
            S[o + 256] = s;
            tot[tid] = s;
        }
        __syncthreads();
        if (tid == 0) {
            unsigned bsum = 0;
            for (int p = 0; p < 52; ++p) {
                base[p] = bsum;
                cnt[m * 52 + p] = tot[p];
                cnt[104 + m * 52 + p] = bsum;
                bsum += tot[p];
            }
        }
        __syncthreads();
        for (int g = tid; g < 13364; g += 256) {
            int pair = g / 257;
            ro[g] = base[pair] + S[g];
        }
        __syncthreads();
    }
}

// grid 512 = (b<<8)|y, block 256
__global__ void k_scatter_rows(const unsigned char* __restrict__ pl,
                               const unsigned char* __restrict__ tl,
                               const unsigned int* __restrict__ rowoff,
                               unsigned short* __restrict__ listP,
                               unsigned short* __restrict__ listT) {
    __shared__ unsigned lh[52];
    __shared__ unsigned lb[52];
    int tid = threadIdx.x;
    int b = blockIdx.x >> 8, y = blockIdx.x & 255;
    if (tid < 52) lh[tid] = 0;
    __syncthreads();
    const unsigned char* Lp = pl + (b << 16);
    const unsigned char* Lt = tl + (b << 16);
    int hw = (y << 8) | tid;
    int cp = Lp[hw];
    int ct = Lt[hw];
    bool bnp = is_boundary(Lp, hw, cp);
    bool bnt = is_boundary(Lt, hw, ct);
    unsigned rp = 0, rt = 0;
    if (bnp) rp = atomicAdd(&lh[cp], 1u);
    if (bnt) rt = atomicAdd(&lh[26 + ct], 1u);
    __syncthreads();
    if (tid < 26)
        lb[tid] = rowoff[(b * 26 + tid) * 257 + y];
    else if (tid < 52)
        lb[tid] = rowoff[13364 + (b * 26 + (tid - 26)) * 257 + y];
    __syncthreads();
    if (bnp) listP[lb[cp] + rp] = (unsigned short)hw;
    if (bnt) listT[lb[26 + ct] + rt] = (unsigned short)hw;
}

#define TCAP 12288
// grid (16, 52, 2), block 256: exact nearest-target via expanding ring over row buckets
__global__ __launch_bounds__(256) void k_ring(
        const unsigned int* __restrict__ cnt,
        const unsigned int* __restrict__ rowoff,
        const unsigned short* __restrict__ listP,
        const unsigned short* __restrict__ listT,
        float* __restrict__ minP, float* __restrict__ minT) {
    int pair = blockIdx.y;
    int dir = blockIdx.z;
    unsigned ns = cnt[dir ? 52 + pair : pair];
    unsigned i0 = (unsigned)blockIdx.x << 8;
    if (i0 >= ns) return;
    unsigned nt = cnt[dir ? pair : 52 + pair];
    unsigned offs = cnt[dir ? 156 + pair : 104 + pair];
    unsigned offt = cnt[dir ? 104 + pair : 156 + pair];
    const unsigned short* src = dir ? listT : listP;
    const unsigned short* tgt = dir ? listP : listT;
    const unsigned* roT = rowoff + (dir ? 0 : 13364) + pair * 257;
    float* outv = dir ? minT : minP;

    __shared__ unsigned rs_[257];
    __shared__ unsigned short lt[TCAP];
    int tid = threadIdx.x;
    for (int t = tid; t < 257; t += 256) rs_[t] = roT[t] - offt;
    bool staged = nt <= TCAP;
    if (staged)
        for (unsigned i = tid; i < nt; i += 256) lt[i] = tgt[offt + i];
    __syncthreads();

    for (unsigned ib = i0; ib < ns; ib += (gridDim.x << 8)) {
        unsigned i = ib + tid;
        if (i >= ns) continue;
        unsigned h = src[offs + i];
        float fx = (float)(h & 255u);
        int sy = (int)(h >> 8);
        float best = 3e9f;
        if (staged) {
            for (int k = 0; k < 256; ++k) {
                float k2 = (float)(k * k);
                if (k2 >= best) break;
                int ra = sy - k, rb = sy + k;
                if (ra < 0 && rb > 255) break;
                if (ra >= 0) {
                    unsigned e = rs_[ra + 1];
                    for (unsigned j = rs_[ra]; j < e; ++j) {
                        float dx = fx - (float)(lt[j] & 255u);
                        best = fminf(best, fmaf(dx, dx, k2));
                    }
                }
                if (k && rb < 256) {
                    unsigned e = rs_[rb + 1];
                    for (unsigned j = rs_[rb]; j < e; ++j) {
                        float dx = fx - (float)(lt[j] & 255u);
                        best = fminf(best, fmaf(dx, dx, k2));
                    }
                }
            }
        } else {
            for (int k = 0; k < 256; ++k) {
                float k2 = (float)(k * k);
                if (k2 >= best) break;
                int ra = sy - k, rb = sy + k;
                if (ra < 0 && rb > 255) break;
                if (ra >= 0) {
                    unsigned e = rs_[ra + 1];
                    for (unsigned j = rs_[ra]; j < e; ++j) {
                        float dx = fx - (float)(tgt[offt + j] & 255u);
                        best = fminf(best, fmaf(dx, dx, k2));
                    }
                }
                if (k && rb < 256) {
                    unsigned e = rs_[rb + 1];
                    for (unsigned j = rs_[rb]; j < e; ++j) {
                        float dx = fx - (float)(tgt[offt + j] & 255u);
                        best = fminf(best, fmaf(dx, dx, k2));
                    }
                }
            }
        }
        outv[offs + i] = best;
    }
}

// grid: (pair=52, dir=2), block 256
__global__ void k_select(const unsigned int* __restrict__ cnt,
                         const float* __restrict__ minP, const float* __restrict__ minT,
                         float* __restrict__ res) {
    int pair = blockIdx.x;
    int dir = blockIdx.y;
    unsigned ns   = dir == 0 ? cnt[pair]       : cnt[52 + pair];
    unsigned nt   = dir == 0 ? cnt[52 + pair]  : cnt[pair];
    unsigned offs = dir == 0 ? cnt[104 + pair] : cnt[156 + pair];
    const float* vals = dir == 0 ? minP : minT;
    int tid = threadIdx.x;

    if (ns == 0) { if (tid == 0) res[pair * 2 + dir] = nanf(""); return; }
    if (nt == 0) { if (tid == 0) res[pair * 2 + dir] = sqrtf(1e10f); return; }

    __shared__ unsigned hist[1024];
    __shared__ unsigned f1[128], f2[128];
    __shared__ int s_binlo, s_binhi, s_below_lo, s_below_hi;

    for (int i = tid; i < 1024; i += 256) hist[i] = 0;
    __syncthreads();
    for (unsigned i = tid; i < ns; i += 256) {
        int v = (int)vals[offs + i];
        atomicAdd(&hist[v >> 7], 1u);
    }
    __syncthreads();

    float idxf = 0.95f * ((float)ns - 1.0f);
    if (idxf < 0.f) idxf = 0.f;
    int klo = (int)floorf(idxf);
    int khi = (int)ceilf(idxf);

    if (tid == 0) {
        unsigned cum = 0;
        int binlo = -1, binhi = -1, below_lo = 0, below_hi = 0;
        for (int bkt = 0; bkt < 1024; ++bkt) {
            unsigned h = hist[bkt];
            if (binlo < 0 && cum + h > (unsigned)klo) { binlo = bkt; below_lo = (int)cum; }
            if (binhi < 0 && cum + h > (unsigned)khi) { binhi = bkt; below_hi = (int)cum; }
            cum += h;
            if (binhi >= 0) break;
        }
        s_binlo = binlo; s_binhi = binhi; s_below_lo = below_lo; s_below_hi = below_hi;
    }
    __syncthreads();
    if (tid < 128) { f1[tid] = 0; f2[tid] = 0; }
    __syncthreads();
    int binlo = s_binlo, binhi = s_binhi;
    for (unsigned i = tid; i < ns; i += 256) {
        int v = (int)vals[offs + i];
        int bkt = v >> 7;
        if (bkt == binlo) atomicAdd(&f1[v & 127], 1u);
        if (bkt == binhi && binhi != binlo) atomicAdd(&f2[v & 127], 1u);
    }
    __syncthreads();
    if (tid == 0) {
        int rlo = klo - s_below_lo;
        unsigned cum = 0; int d2lo = binlo << 7, d2hi = binhi << 7;
        for (int j = 0; j < 128; ++j) {
            cum += f1[j];
            if ((int)cum > rlo) { d2lo = (binlo << 7) + j; break; }
        }
        if (binhi == binlo) {
            int rhi = khi - s_below_lo;
            cum = 0;
            for (int j = 0; j < 128; ++j) {
                cum += f1[j];
                if ((int)cum > rhi) { d2hi = (binlo << 7) + j; break; }
            }
        } else {
            int rhi = khi - s_below_hi;
            cum = 0;
            for (int j = 0; j < 128; ++j) {
                cum += f2[j];
                if ((int)cum > rhi) { d2hi = (binhi << 7) + j; break; }
            }
        }
        float vlo = sqrtf((float)d2lo);
        float vhi = sqrtf((float)d2hi);
        float frac = idxf - floorf(idxf);
        res[pair * 2 + dir] = vlo + (vhi - vlo) * frac;
    }
}

__global__ void k_final(const unsigned int* __restrict__ cnt, const float* __restrict__ res,
                        float* __restrict__ out) {
    if (threadIdx.x != 0 || blockIdx.x != 0) return;
    float total = 0.f, nvalid = 0.f;
    bool anyv = false;
    for (int b = 0; b < NB; ++b) {
        float num = 0.f, den = 0.f;
        for (int c = 0; c < NC; ++c) {
            int pair = b * NC + c;
            bool present = cnt[52 + pair] > 0;
            float dpt = res[pair * 2];
            float dtp = res[pair * 2 + 1];
            float hd;
            if (isnan(dpt) || isnan(dtp)) hd = nanf("");
            else hd = fmaxf(dpt, dtp);
            if (present) { num += hd; den += 1.f; }
        }
        float bm = num / fmaxf(den, 1.f);
        if (den > 0.f) { total += bm; nvalid += 1.f; anyv = true; }
    }
    out[0] = anyv ? (total / fmaxf(nvalid, 1.f)) : INFINITY;
}

extern "C" void kernel_launch(void* const* d_in, const int* in_sizes, int n_in,
                              void* d_out, int out_size, void* d_ws, size_t ws_size,
                              hipStream_t stream) {
    const float* pred = (const float*)d_in[0];
    const float* targ = (const float*)d_in[1];
    float* out = (float*)d_out;
    char* ws = (char*)d_ws;

    unsigned char* pl = (unsigned char*)(ws + PL_OFF);
    unsigned char* tl = (unsigned char*)(ws + TL_OFF);
    unsigned int* cnt = (unsigned int*)(ws + CNT_OFF);
    float* res = (float*)(ws + RES_OFF);
    unsigned int* rowoff = (unsigned int*)(ws + ROWOFF_OFF);
    unsigned int* rowcnt = (unsigned int*)(ws + ROWCNT_OFF);   // overlays minP (dead by then)
    unsigned short* listP = (unsigned short*)(ws + LISTP_OFF);
    unsigned short* listT = (unsigned short*)(ws + LISTT_OFF);
    float* minP = (float*)(ws + MINP_OFF);
    float* minT = (float*)(ws + MINT_OFF);

    k_labels<<<256, 128, 0, stream>>>((const float4*)pred, (const float4*)targ,
                                      (uchar4*)pl, (uchar4*)tl);
    k_count_rows<<<512, 256, 0, stream>>>(pl, tl, rowcnt);
    k_prefix_rows<<<1, 256, 0, stream>>>(rowcnt, rowoff, cnt);
    k_scatter_rows<<<512, 256, 0, stream>>>(pl, tl, rowoff, listP, listT);
    k_ring<<<dim3(16, 52, 2), 256, 0, stream>>>(cnt, rowoff, listP, listT, minP, minT);
    k_select<<<dim3(52, 2), 256, 0, stream>>>(cnt, minP, minT, res);
    k_final<<<1, 64, 0, stream>>>(cnt, res, out);
}

// Round 7
// 76.286 us; speedup vs baseline: 16.7340x; 1.1636x over previous
//
#include <hip/hip_runtime.h>
#include <math.h>

#define HW 65536
#define NC 26
#define NB 2

// ws layout (bytes). cnt u32: [0..51] cntP, [52..103] cntT, [104..155] offP, [156..207] offT
#define PL_OFF     0         // u8 [2][65536]
#define TL_OFF     131072    // u8 [2][65536]
#define CNT_OFF    262144    // 208 u32 used
#define RES_OFF    263424    // f32 res[52][2]
#define ROWOFF_OFF 264192    // u32 [2][52][257] = 106912 B
#define LISTP_OFF  371104    // u16[131072]
#define LISTT_OFF  633248    // u16[131072]
#define MINP_OFF   895392    // f32[131072]
#define MINT_OFF   1419680   // f32[131072]  (ends 1943968)
#define ROWCNT_OFF MINP_OFF  // u32 [2][52][256] = 106496 B, dead before minP written

__global__ void k_labels(const float4* __restrict__ pred, const float4* __restrict__ targ,
                         uchar4* __restrict__ pl, uchar4* __restrict__ tl) {
    int idx = blockIdx.x * 128 + threadIdx.x;   // 0..32767
    if (idx >= (NB * HW / 4)) return;
    int b = idx >> 14, q = idx & 16383;
    const float4* p = pred + ((size_t)b * NC << 14) + q;
    const float4* t = targ + ((size_t)b * NC << 14) + q;
    float4 bp = p[0]; uchar4 ap = {0, 0, 0, 0};
    float4 bt = t[0]; uchar4 at = {0, 0, 0, 0};
#pragma unroll
    for (int c = 1; c < NC; ++c) {
        float4 vp = p[(size_t)c << 14];
        if (vp.x > bp.x) { bp.x = vp.x; ap.x = (unsigned char)c; }
        if (vp.y > bp.y) { bp.y = vp.y; ap.y = (unsigned char)c; }
        if (vp.z > bp.z) { bp.z = vp.z; ap.z = (unsigned char)c; }
        if (vp.w > bp.w) { bp.w = vp.w; ap.w = (unsigned char)c; }
        float4 vt = t[(size_t)c << 14];
        if (vt.x > bt.x) { bt.x = vt.x; at.x = (unsigned char)c; }
        if (vt.y > bt.y) { bt.y = vt.y; at.y = (unsigned char)c; }
        if (vt.z > bt.z) { bt.z = vt.z; at.z = (unsigned char)c; }
        if (vt.w > bt.w) { bt.w = vt.w; at.w = (unsigned char)c; }
    }
    pl[idx] = ap;
    tl[idx] = at;
}

__device__ __forceinline__ bool is_boundary(const unsigned char* __restrict__ L, int hw, int c) {
    int y = hw >> 8, x = hw & 255;
    if (y == 0 || y == 255 || x == 0 || x == 255) return true;
    return (int)L[hw - 256] != c || (int)L[hw + 256] != c ||
           (int)L[hw - 1]   != c || (int)L[hw + 1]   != c;
}

// grid 512 = (b<<8)|y, block 256 (tid = x). rowcnt: [2][52][256]
__global__ void k_count_rows(const unsigned char* __restrict__ pl,
                             const unsigned char* __restrict__ tl,
                             unsigned int* __restrict__ rowcnt) {
    __shared__ unsigned lh[52];
    int tid = threadIdx.x;
    int b = blockIdx.x >> 8, y = blockIdx.x & 255;
    if (tid < 52) lh[tid] = 0;
    __syncthreads();
    const unsigned char* Lp = pl + (b << 16);
    const unsigned char* Lt = tl + (b << 16);
    int hw = (y << 8) | tid;
    int cp = Lp[hw];
    if (is_boundary(Lp, hw, cp)) atomicAdd(&lh[cp], 1u);
    int ct = Lt[hw];
    if (is_boundary(Lt, hw, ct)) atomicAdd(&lh[26 + ct], 1u);
    __syncthreads();
    if (tid < 26)
        rowcnt[(((b * 26 + tid) << 8) | y)] = lh[tid];
    else if (tid < 52)
        rowcnt[13312 + (((b * 26 + (tid - 26)) << 8) | y)] = lh[tid];
}

// grid 2 (m), block 256. rowcnt[m][52][256] -> rowoff[m][52][257] (absolute), cnt totals+bases
__global__ void k_prefix_rows(const unsigned int* __restrict__ rowcnt,
                              unsigned int* __restrict__ rowoff,
                              unsigned int* __restrict__ cnt) {
    __shared__ unsigned S[52 * 257];
    __shared__ unsigned tot[52], base[64];
    int m = blockIdx.x;
    int tid = threadIdx.x;
    const unsigned* rc = rowcnt + m * 13312;
    unsigned* ro = rowoff + m * 13364;
    for (int g = tid; g < 13312; g += 256)
        S[(g >> 8) * 257 + (g & 255)] = rc[g];
    __syncthreads();
    int wid = tid >> 6, lane = tid & 63;
    for (int p = wid; p < 52; p += 4) {
        int o = p * 257 + lane * 4;
        unsigned v0 = S[o], v1 = S[o + 1], v2 = S[o + 2], v3 = S[o + 3];
        unsigned s01 = v0 + v1;
        unsigned s = s01 + v2 + v3;
        unsigned incl = s;
#pragma unroll
        for (int d = 1; d < 64; d <<= 1) {
            unsigned u = __shfl_up(incl, d, 64);
            if (lane >= d) incl += u;
        }
        unsigned excl = incl - s;
        S[o] = excl; S[o + 1] = excl + v0; S[o + 2] = excl + s01; S[o + 3] = excl + s01 + v2;
        unsigned total = __shfl(incl, 63, 64);
        if (lane == 0) { S[p * 257 + 256] = total; tot[p] = total; }
    }
    __syncthreads();
    if (tid < 64) {
        unsigned t = tid < 52 ? tot[tid] : 0u;
        unsigned incl = t;
#pragma unroll
        for (int d = 1; d < 64; d <<= 1) {
            unsigned u = __shfl_up(incl, d, 64);
            if (tid >= d) incl += u;
        }
        if (tid < 52) {
            unsigned excl = incl - t;
            base[tid] = excl;
            cnt[m * 52 + tid] = t;
            cnt[104 + m * 52 + tid] = excl;
        }
    }
    __syncthreads();
    for (int g = tid; g < 13364; g += 256)
        ro[g] = base[g / 257] + S[g];
}

// grid 512 = (b<<8)|y, block 256
__global__ void k_scatter_rows(const unsigned char* __restrict__ pl,
                               const unsigned char* __restrict__ tl,
                               const unsigned int* __restrict__ rowoff,
                               unsigned short* __restrict__ listP,
                               unsigned short* __restrict__ listT) {
    __shared__ unsigned lh[52];
    __shared__ unsigned lb[52];
    int tid = threadIdx.x;
    int b = blockIdx.x >> 8, y = blockIdx.x & 255;
    if (tid < 52) lh[tid] = 0;
    __syncthreads();
    const unsigned char* Lp = pl + (b << 16);
    const unsigned char* Lt = tl + (b << 16);
    int hw = (y << 8) | tid;
    int cp = Lp[hw];
    int ct = Lt[hw];
    bool bnp = is_boundary(Lp, hw, cp);
    bool bnt = is_boundary(Lt, hw, ct);
    unsigned rp = 0, rt = 0;
    if (bnp) rp = atomicAdd(&lh[cp], 1u);
    if (bnt) rt = atomicAdd(&lh[26 + ct], 1u);
    __syncthreads();
    if (tid < 26)
        lb[tid] = rowoff[(b * 26 + tid) * 257 + y];
    else if (tid < 52)
        lb[tid] = rowoff[13364 + (b * 26 + (tid - 26)) * 257 + y];
    __syncthreads();
    if (bnp) listP[lb[cp] + rp] = (unsigned short)hw;
    if (bnt) listT[lb[26 + ct] + rt] = (unsigned short)hw;
}

// grid (24, 52, 2), block 128: exact nearest-target via expanding ring over row buckets.
// Targets read through L1/L2 (per-pair list ~5KB, cache-resident); only rs_ (1KB) in LDS.
__global__ __launch_bounds__(128) void k_ring(
        const unsigned int* __restrict__ cnt,
        const unsigned int* __restrict__ rowoff,
        const unsigned short* __restrict__ listP,
        const unsigned short* __restrict__ listT,
        float* __restrict__ minP, float* __restrict__ minT) {
    int pair = blockIdx.y;
    int dir = blockIdx.z;
    unsigned ns = cnt[dir ? 52 + pair : pair];
    unsigned i0 = blockIdx.x * 128u;
    if (i0 >= ns) return;
    unsigned offs = cnt[dir ? 156 + pair : 104 + pair];
    unsigned offt = cnt[dir ? 104 + pair : 156 + pair];
    const unsigned short* src = dir ? listT : listP;
    const unsigned short* tgt = dir ? listP : listT;
    const unsigned* roT = rowoff + (dir ? 0 : 13364) + pair * 257;
    float* outv = dir ? minT : minP;

    __shared__ unsigned rs_[257];
    int tid = threadIdx.x;
    for (int t = tid; t < 257; t += 128) rs_[t] = roT[t] - offt;
    __syncthreads();

    unsigned stride = gridDim.x * 128u;
    for (unsigned ib = i0; ib < ns; ib += stride) {
        unsigned i = ib + tid;
        if (i >= ns) continue;
        unsigned h = src[offs + i];
        float fx = (float)(h & 255u);
        int sy = (int)(h >> 8);
        float best = 3e9f;
        for (int k = 0; k < 256; ++k) {
            float k2 = (float)(k * k);
            if (k2 >= best) break;
            int ra = sy - k, rb = sy + k;
            if (ra < 0 && rb > 255) break;
            if (ra >= 0) {
                unsigned jb = rs_[ra], je = rs_[ra + 1];
                for (unsigned j = jb; j < je; ++j) {
                    float dx = fx - (float)(tgt[offt + j] & 255u);
                    best = fminf(best, fmaf(dx, dx, k2));
                }
            }
            if (k && rb < 256) {
                unsigned jb = rs_[rb], je = rs_[rb + 1];
                for (unsigned j = jb; j < je; ++j) {
                    float dx = fx - (float)(tgt[offt + j] & 255u);
                    best = fminf(best, fmaf(dx, dx, k2));
                }
            }
        }
        outv[offs + i] = best;
    }
}

// grid: (pair=52, dir=2), block 256
__global__ void k_select(const unsigned int* __restrict__ cnt,
                         const float* __restrict__ minP, const float* __restrict__ minT,
                         float* __restrict__ res) {
    int pair = blockIdx.x;
    int dir = blockIdx.y;
    unsigned ns   = dir == 0 ? cnt[pair]       : cnt[52 + pair];
    unsigned nt   = dir == 0 ? cnt[52 + pair]  : cnt[pair];
    unsigned offs = dir == 0 ? cnt[104 + pair] : cnt[156 + pair];
    const float* vals = dir == 0 ? minP : minT;
    int tid = threadIdx.x;

    if (ns == 0) { if (tid == 0) res[pair * 2 + dir] = nanf(""); return; }
    if (nt == 0) { if (tid == 0) res[pair * 2 + dir] = sqrtf(1e10f); return; }

    __shared__ unsigned hist[1024];
    __shared__ unsigned f1[128], f2[128];
    __shared__ int s_binlo, s_binhi, s_below_lo, s_below_hi;

    for (int i = tid; i < 1024; i += 256) hist[i] = 0;
    __syncthreads();
    for (unsigned i = tid; i < ns; i += 256) {
        int v = (int)vals[offs + i];
        atomicAdd(&hist[v >> 7], 1u);
    }
    __syncthreads();

    float idxf = 0.95f * ((float)ns - 1.0f);
    if (idxf < 0.f) idxf = 0.f;
    int klo = (int)floorf(idxf);
    int khi = (int)ceilf(idxf);

    if (tid == 0) {
        unsigned cum = 0;
        int binlo = -1, binhi = -1, below_lo = 0, below_hi = 0;
        for (int bkt = 0; bkt < 1024; ++bkt) {
            unsigned h = hist[bkt];
            if (binlo < 0 && cum + h > (unsigned)klo) { binlo = bkt; below_lo = (int)cum; }
            if (binhi < 0 && cum + h > (unsigned)khi) { binhi = bkt; below_hi = (int)cum; }
            cum += h;
            if (binhi >= 0) break;
        }
        s_binlo = binlo; s_binhi = binhi; s_below_lo = below_lo; s_below_hi = below_hi;
    }
    __syncthreads();
    if (tid < 128) { f1[tid] = 0; f2[tid] = 0; }
    __syncthreads();
    int binlo = s_binlo, binhi = s_binhi;
    for (unsigned i = tid; i < ns; i += 256) {
        int v = (int)vals[offs + i];
        int bkt = v >> 7;
        if (bkt == binlo) atomicAdd(&f1[v & 127], 1u);
        if (bkt == binhi && binhi != binlo) atomicAdd(&f2[v & 127], 1u);
    }
    __syncthreads();
    if (tid == 0) {
        int rlo = klo - s_below_lo;
        unsigned cum = 0; int d2lo = binlo << 7, d2hi = binhi << 7;
        for (int j = 0; j < 128; ++j) {
            cum += f1[j];
            if ((int)cum > rlo) { d2lo = (binlo << 7) + j; break; }
        }
        if (binhi == binlo) {
            int rhi = khi - s_below_lo;
            cum = 0;
            for (int j = 0; j < 128; ++j) {
                cum += f1[j];
                if ((int)cum > rhi) { d2hi = (binlo << 7) + j; break; }
            }
        } else {
            int rhi = khi - s_below_hi;
            cum = 0;
            for (int j = 0; j < 128; ++j) {
                cum += f2[j];
                if ((int)cum > rhi) { d2hi = (binhi << 7) + j; break; }
            }
        }
        float vlo = sqrtf((float)d2lo);
        float vhi = sqrtf((float)d2hi);
        float frac = idxf - floorf(idxf);
        res[pair * 2 + dir] = vlo + (vhi - vlo) * frac;
    }
}

__global__ void k_final(const unsigned int* __restrict__ cnt, const float* __restrict__ res,
                        float* __restrict__ out) {
    if (threadIdx.x != 0 || blockIdx.x != 0) return;
    float total = 0.f, nvalid = 0.f;
    bool anyv = false;
    for (int b = 0; b < NB; ++b) {
        float num = 0.f, den = 0.f;
        for (int c = 0; c < NC; ++c) {
            int pair = b * NC + c;
            bool present = cnt[52 + pair] > 0;
            float dpt = res[pair * 2];
            float dtp = res[pair * 2 + 1];
            float hd;
            if (isnan(dpt) || isnan(dtp)) hd = nanf("");
            else hd = fmaxf(dpt, dtp);
            if (present) { num += hd; den += 1.f; }
        }
        float bm = num / fmaxf(den, 1.f);
        if (den > 0.f) { total += bm; nvalid += 1.f; anyv = true; }
    }
    out[0] = anyv ? (total / fmaxf(nvalid, 1.f)) : INFINITY;
}

extern "C" void kernel_launch(void* const* d_in, const int* in_sizes, int n_in,
                              void* d_out, int out_size, void* d_ws, size_t ws_size,
                              hipStream_t stream) {
    const float* pred = (const float*)d_in[0];
    const float* targ = (const float*)d_in[1];
    float* out = (float*)d_out;
    char* ws = (char*)d_ws;

    unsigned char* pl = (unsigned char*)(ws + PL_OFF);
    unsigned char* tl = (unsigned char*)(ws + TL_OFF);
    unsigned int* cnt = (unsigned int*)(ws + CNT_OFF);
    float* res = (float*)(ws + RES_OFF);
    unsigned int* rowoff = (unsigned int*)(ws + ROWOFF_OFF);
    unsigned int* rowcnt = (unsigned int*)(ws + ROWCNT_OFF);   // overlays minP (dead by then)
    unsigned short* listP = (unsigned short*)(ws + LISTP_OFF);
    unsigned short* listT = (unsigned short*)(ws + LISTT_OFF);
    float* minP = (float*)(ws + MINP_OFF);
    float* minT = (float*)(ws + MINT_OFF);

    k_labels<<<256, 128, 0, stream>>>((const float4*)pred, (const float4*)targ,
                                      (uchar4*)pl, (uchar4*)tl);
    k_count_rows<<<512, 256, 0, stream>>>(pl, tl, rowcnt);
    k_prefix_rows<<<2, 256, 0, stream>>>(rowcnt, rowoff, cnt);
    k_scatter_rows<<<512, 256, 0, stream>>>(pl, tl, rowoff, listP, listT);
    k_ring<<<dim3(24, 52, 2), 128, 0, stream>>>(cnt, rowoff, listP, listT, minP, minT);
    k_select<<<dim3(52, 2), 256, 0, stream>>>(cnt, minP, minT, res);
    k_final<<<1, 64, 0, stream>>>(cnt, res, out);
}

// Round 8
// 71.399 us; speedup vs baseline: 17.8792x; 1.0684x over previous
//
#include <hip/hip_runtime.h>
#include <math.h>

#define HW 65536
#define NC 26
#define NB 2

// ws layout (bytes). cnt u32: [0..51] cntP, [52..103] cntT, [104..155] offP,
// [156..207] offT, [208..259] curP, [260..311] curT  (ws_size ~256MB, plenty)
#define PL_OFF    0          // u8 [2][65536]
#define TL_OFF    131072     // u8 [2][65536]
#define CNT_OFF   262144     // 312 u32
#define RES_OFF   263424     // f32 res[52][2]
#define LISTP_OFF 264192     // u16[131072]
#define LISTT_OFF 526336     // u16[131072]
#define MINP_OFF  788480     // f32[131072]
#define MINT_OFF  1312768    // f32[131072]
#define BMP_OFF   1837056    // u32 [2][52][256][8] = 851968 B (16B aligned)

__global__ void k_labels(const float4* __restrict__ pred, const float4* __restrict__ targ,
                         uchar4* __restrict__ pl, uchar4* __restrict__ tl,
                         unsigned int* __restrict__ cnt) {
    int tid = threadIdx.x;
    if (blockIdx.x == 0) {
        for (int i = tid; i < 312; i += 128) cnt[i] = 0;
    }
    int idx = blockIdx.x * 128 + tid;   // 0..32767
    if (idx >= (NB * HW / 4)) return;
    int b = idx >> 14, q = idx & 16383;
    const float4* p = pred + ((size_t)b * NC << 14) + q;
    const float4* t = targ + ((size_t)b * NC << 14) + q;
    float4 bp = p[0]; uchar4 ap = {0, 0, 0, 0};
    float4 bt = t[0]; uchar4 at = {0, 0, 0, 0};
#pragma unroll
    for (int c = 1; c < NC; ++c) {
        float4 vp = p[(size_t)c << 14];
        if (vp.x > bp.x) { bp.x = vp.x; ap.x = (unsigned char)c; }
        if (vp.y > bp.y) { bp.y = vp.y; ap.y = (unsigned char)c; }
        if (vp.z > bp.z) { bp.z = vp.z; ap.z = (unsigned char)c; }
        if (vp.w > bp.w) { bp.w = vp.w; ap.w = (unsigned char)c; }
        float4 vt = t[(size_t)c << 14];
        if (vt.x > bt.x) { bt.x = vt.x; at.x = (unsigned char)c; }
        if (vt.y > bt.y) { bt.y = vt.y; at.y = (unsigned char)c; }
        if (vt.z > bt.z) { bt.z = vt.z; at.z = (unsigned char)c; }
        if (vt.w > bt.w) { bt.w = vt.w; at.w = (unsigned char)c; }
    }
    pl[idx] = ap;
    tl[idx] = at;
}

__device__ __forceinline__ bool is_boundary(const unsigned char* __restrict__ L, int hw, int c) {
    int y = hw >> 8, x = hw & 255;
    if (y == 0 || y == 255 || x == 0 || x == 255) return true;
    return (int)L[hw - 256] != c || (int)L[hw + 256] != c ||
           (int)L[hw - 1]   != c || (int)L[hw + 1]   != c;
}

// grid 512 = (b<<8)|y, block 256. Builds boundary bitmaps [m][pair][y][8]u32 + class totals.
__global__ void k_rowbm(const unsigned char* __restrict__ pl,
                        const unsigned char* __restrict__ tl,
                        unsigned int* __restrict__ bmp,
                        unsigned int* __restrict__ cnt) {
    __shared__ unsigned bm[52][8];
    __shared__ unsigned lh[52];
    int tid = threadIdx.x;
    int b = blockIdx.x >> 8, y = blockIdx.x & 255;
    for (int i = tid; i < 416; i += 256) ((unsigned*)bm)[i] = 0;
    if (tid < 52) lh[tid] = 0;
    __syncthreads();
    const unsigned char* Lp = pl + (b << 16);
    const unsigned char* Lt = tl + (b << 16);
    int hw = (y << 8) | tid;
    int cp = Lp[hw];
    if (is_boundary(Lp, hw, cp)) {
        atomicOr(&bm[cp][tid >> 5], 1u << (tid & 31));
        atomicAdd(&lh[cp], 1u);
    }
    int ct = Lt[hw];
    if (is_boundary(Lt, hw, ct)) {
        atomicOr(&bm[26 + ct][tid >> 5], 1u << (tid & 31));
        atomicAdd(&lh[26 + ct], 1u);
    }
    __syncthreads();
    // write out: index idx = class-slot (0..51), w = word
    for (int i = tid; i < 416; i += 256) {
        int idx = i >> 3, w = i & 7;
        int m = idx < 26 ? 0 : 1;
        int c = idx < 26 ? idx : idx - 26;
        bmp[(((m * 52 + b * 26 + c) << 8) | y) * 8 + w] = bm[idx][w];
    }
    if (tid < 26) { if (lh[tid]) atomicAdd(&cnt[b * 26 + tid], lh[tid]); }
    else if (tid < 52) { if (lh[tid]) atomicAdd(&cnt[52 + b * 26 + (tid - 26)], lh[tid]); }
}

__global__ void k_prefix(unsigned int* __restrict__ cnt) {
    if (threadIdx.x != 0 || blockIdx.x != 0) return;
    unsigned s = 0;
    for (int i = 0; i < 52; ++i) { cnt[104 + i] = s; cnt[208 + i] = s; s += cnt[i]; }
    s = 0;
    for (int i = 0; i < 52; ++i) { cnt[156 + i] = s; cnt[260 + i] = s; s += cnt[52 + i]; }
}

// grid 512 = (b<<8)|y, block 256: class-order compaction (order within class arbitrary)
__global__ void k_scatter(const unsigned char* __restrict__ pl,
                          const unsigned char* __restrict__ tl,
                          unsigned int* __restrict__ cnt,
                          unsigned short* __restrict__ listP,
                          unsigned short* __restrict__ listT) {
    __shared__ unsigned lh[52];
    __shared__ unsigned lb[52];
    int tid = threadIdx.x;
    int b = blockIdx.x >> 8, y = blockIdx.x & 255;
    if (tid < 52) lh[tid] = 0;
    __syncthreads();
    const unsigned char* Lp = pl + (b << 16);
    const unsigned char* Lt = tl + (b << 16);
    int hw = (y << 8) | tid;
    int cp = Lp[hw];
    int ct = Lt[hw];
    bool bnp = is_boundary(Lp, hw, cp);
    bool bnt = is_boundary(Lt, hw, ct);
    unsigned rp = 0, rt = 0;
    if (bnp) rp = atomicAdd(&lh[cp], 1u);
    if (bnt) rt = atomicAdd(&lh[26 + ct], 1u);
    __syncthreads();
    if (tid < 26)
        lb[tid] = lh[tid] ? atomicAdd(&cnt[208 + b * 26 + tid], lh[tid]) : 0u;
    else if (tid < 52)
        lb[tid] = lh[tid] ? atomicAdd(&cnt[260 + b * 26 + (tid - 26)], lh[tid]) : 0u;
    __syncthreads();
    if (bnp) listP[lb[cp] + rp] = (unsigned short)hw;
    if (bnt) listT[lb[26 + ct] + rt] = (unsigned short)hw;
}

__device__ __forceinline__ int row_dxmin(const unsigned (*sb)[8], int r, int xw, int xb) {
    int dxmin = 999;
    unsigned m = sb[r][xw];
    unsigned le = 0xFFFFFFFFu >> (31 - xb);   // bits 0..xb
    unsigned lm = m & le;
    if (lm) dxmin = xb - (31 - __clz(lm));
    unsigned rm = m & ~le;
    if (rm) { int d = (__ffs(rm) - 1) - xb; dxmin = min(dxmin, d); }
#pragma unroll 1
    for (int w = xw - 1; w >= 0; --w) {
        unsigned mm = sb[r][w];
        if (mm) { int d = xb + ((xw - w) << 5) - (31 - __clz(mm)); dxmin = min(dxmin, d); break; }
    }
#pragma unroll 1
    for (int w = xw + 1; w < 8; ++w) {
        unsigned mm = sb[r][w];
        if (mm) { int d = ((w - xw) << 5) + (__ffs(mm) - 1) - xb; dxmin = min(dxmin, d); break; }
    }
    return dxmin;
}

// grid (20, 52, 2), block 128: exact nearest boundary pixel via expanding ring
// over the target-class bitmap (8KB in LDS); per-row nearest bit via clz/ffs.
__global__ __launch_bounds__(128) void k_ring(
        const unsigned int* __restrict__ cnt,
        const unsigned int* __restrict__ bmp,
        const unsigned short* __restrict__ listP,
        const unsigned short* __restrict__ listT,
        float* __restrict__ minP, float* __restrict__ minT) {
    int pair = blockIdx.y;
    int dir = blockIdx.z;
    unsigned ns = cnt[dir ? 52 + pair : pair];
    unsigned i0 = blockIdx.x * 128u;
    if (i0 >= ns) return;
    unsigned nt = cnt[dir ? pair : 52 + pair];
    if (nt == 0) return;   // k_select overrides with sqrt(1e10); minP never read
    unsigned offs = cnt[dir ? 156 + pair : 104 + pair];
    const unsigned short* src = dir ? listT : listP;
    float* outv = dir ? minT : minP;

    __shared__ unsigned sb[256][8];
    int tid = threadIdx.x;
    {   // stage target bitmap: dir0 targets=T (m=1), dir1 targets=P (m=0)
        const uint4* gb = (const uint4*)(bmp + ((unsigned)((dir ? 0 : 52) + pair) << 11));
        uint4* s4 = (uint4*)sb;
#pragma unroll
        for (int t = 0; t < 4; ++t) s4[tid + t * 128] = gb[tid + t * 128];
    }
    __syncthreads();

    unsigned stride = gridDim.x * 128u;
    for (unsigned ib = i0; ib < ns; ib += stride) {
        unsigned i = ib + tid;
        if (i >= ns) continue;
        unsigned h = src[offs + i];
        int x = (int)(h & 255u);
        int sy = (int)(h >> 8);
        int xw = x >> 5, xb = x & 31;
        int best = 0x40000000;
        for (int k = 0; k < 256; ++k) {
            int k2 = k * k;
            if (k2 >= best) break;
            int ra = sy - k, rb = sy + k;
            if (ra < 0 && rb > 255) break;
            if (ra >= 0) {
                int dx = row_dxmin(sb, ra, xw, xb);
                if (dx < 999) best = min(best, k2 + dx * dx);
            }
            if (k && rb < 256) {
                int dx = row_dxmin(sb, rb, xw, xb);
                if (dx < 999) best = min(best, k2 + dx * dx);
            }
        }
        outv[offs + i] = (float)best;
    }
}

// grid: (pair=52, dir=2), block 256
__global__ void k_select(const unsigned int* __restrict__ cnt,
                         const float* __restrict__ minP, const float* __restrict__ minT,
                         float* __restrict__ res) {
    int pair = blockIdx.x;
    int dir = blockIdx.y;
    unsigned ns   = dir == 0 ? cnt[pair]       : cnt[52 + pair];
    unsigned nt   = dir == 0 ? cnt[52 + pair]  : cnt[pair];
    unsigned offs = dir == 0 ? cnt[104 + pair] : cnt[156 + pair];
    const float* vals = dir == 0 ? minP : minT;
    int tid = threadIdx.x;

    if (ns == 0) { if (tid == 0) res[pair * 2 + dir] = nanf(""); return; }
    if (nt == 0) { if (tid == 0) res[pair * 2 + dir] = sqrtf(1e10f); return; }

    __shared__ unsigned hist[1024];
    __shared__ unsigned f1[128], f2[128];
    __shared__ int s_binlo, s_binhi, s_below_lo, s_below_hi;

    for (int i = tid; i < 1024; i += 256) hist[i] = 0;
    __syncthreads();
    for (unsigned i = tid; i < ns; i += 256) {
        int v = (int)vals[offs + i];
        atomicAdd(&hist[v >> 7], 1u);
    }
    __syncthreads();

    float idxf = 0.95f * ((float)ns - 1.0f);
    if (idxf < 0.f) idxf = 0.f;
    int klo = (int)floorf(idxf);
    int khi = (int)ceilf(idxf);

    if (tid == 0) {
        unsigned cum = 0;
        int binlo = -1, binhi = -1, below_lo = 0, below_hi = 0;
        for (int bkt = 0; bkt < 1024; ++bkt) {
            unsigned h = hist[bkt];
            if (binlo < 0 && cum + h > (unsigned)klo) { binlo = bkt; below_lo = (int)cum; }
            if (binhi < 0 && cum + h > (unsigned)khi) { binhi = bkt; below_hi = (int)cum; }
            cum += h;
            if (binhi >= 0) break;
        }
        s_binlo = binlo; s_binhi = binhi; s_below_lo = below_lo; s_below_hi = below_hi;
    }
    __syncthreads();
    if (tid < 128) { f1[tid] = 0; f2[tid] = 0; }
    __syncthreads();
    int binlo = s_binlo, binhi = s_binhi;
    for (unsigned i = tid; i < ns; i += 256) {
        int v = (int)vals[offs + i];
        int bkt = v >> 7;
        if (bkt == binlo) atomicAdd(&f1[v & 127], 1u);
        if (bkt == binhi && binhi != binlo) atomicAdd(&f2[v & 127], 1u);
    }
    __syncthreads();
    if (tid == 0) {
        int rlo = klo - s_below_lo;
        unsigned cum = 0; int d2lo = binlo << 7, d2hi = binhi << 7;
        for (int j = 0; j < 128; ++j) {
            cum += f1[j];
            if ((int)cum > rlo) { d2lo = (binlo << 7) + j; break; }
        }
        if (binhi == binlo) {
            int rhi = khi - s_below_lo;
            cum = 0;
            for (int j = 0; j < 128; ++j) {
                cum += f1[j];
                if ((int)cum > rhi) { d2hi = (binlo << 7) + j; break; }
            }
        } else {
            int rhi = khi - s_below_hi;
            cum = 0;
            for (int j = 0; j < 128; ++j) {
                cum += f2[j];
                if ((int)cum > rhi) { d2hi = (binhi << 7) + j; break; }
            }
        }
        float vlo = sqrtf((float)d2lo);
        float vhi = sqrtf((float)d2hi);
        float frac = idxf - floorf(idxf);
        res[pair * 2 + dir] = vlo + (vhi - vlo) * frac;
    }
}

__global__ void k_final(const unsigned int* __restrict__ cnt, const float* __restrict__ res,
                        float* __restrict__ out) {
    if (threadIdx.x != 0 || blockIdx.x != 0) return;
    float total = 0.f, nvalid = 0.f;
    bool anyv = false;
    for (int b = 0; b < NB; ++b) {
        float num = 0.f, den = 0.f;
        for (int c = 0; c < NC; ++c) {
            int pair = b * NC + c;
            bool present = cnt[52 + pair] > 0;
            float dpt = res[pair * 2];
            float dtp = res[pair * 2 + 1];
            float hd;
            if (isnan(dpt) || isnan(dtp)) hd = nanf("");
            else hd = fmaxf(dpt, dtp);
            if (present) { num += hd; den += 1.f; }
        }
        float bm = num / fmaxf(den, 1.f);
        if (den > 0.f) { total += bm; nvalid += 1.f; anyv = true; }
    }
    out[0] = anyv ? (total / fmaxf(nvalid, 1.f)) : INFINITY;
}

extern "C" void kernel_launch(void* const* d_in, const int* in_sizes, int n_in,
                              void* d_out, int out_size, void* d_ws, size_t ws_size,
                              hipStream_t stream) {
    const float* pred = (const float*)d_in[0];
    const float* targ = (const float*)d_in[1];
    float* out = (float*)d_out;
    char* ws = (char*)d_ws;

    unsigned char* pl = (unsigned char*)(ws + PL_OFF);
    unsigned char* tl = (unsigned char*)(ws + TL_OFF);
    unsigned int* cnt = (unsigned int*)(ws + CNT_OFF);
    float* res = (float*)(ws + RES_OFF);
    unsigned int* bmp = (unsigned int*)(ws + BMP_OFF);
    unsigned short* listP = (unsigned short*)(ws + LISTP_OFF);
    unsigned short* listT = (unsigned short*)(ws + LISTT_OFF);
    float* minP = (float*)(ws + MINP_OFF);
    float* minT = (float*)(ws + MINT_OFF);

    k_labels<<<256, 128, 0, stream>>>((const float4*)pred, (const float4*)targ,
                                      (uchar4*)pl, (uchar4*)tl, cnt);
    k_rowbm<<<512, 256, 0, stream>>>(pl, tl, bmp, cnt);
    k_prefix<<<1, 64, 0, stream>>>(cnt);
    k_scatter<<<512, 256, 0, stream>>>(pl, tl, cnt, listP, listT);
    k_ring<<<dim3(20, 52, 2), 128, 0, stream>>>(cnt, bmp, listP, listT, minP, minT);
    k_select<<<dim3(52, 2), 256, 0, stream>>>(cnt, minP, minT, res);
    k_final<<<1, 64, 0, stream>>>(cnt, res, out);
}